// Round 2
// baseline (477.786 us; speedup 1.0000x reference)
//
#include <hip/hip_runtime.h>
#include <hip/hip_bf16.h>

typedef unsigned short u16;
typedef unsigned int u32;
typedef __attribute__((ext_vector_type(4))) float f32x4;
typedef __attribute__((ext_vector_type(8))) short s16x8;
typedef __attribute__((ext_vector_type(4))) int i32x4;

#define GLD 2048  // G buffer row stride (floats)

__device__ inline u16 f2bf(float f) {
  union { float f; u32 u; } v; v.f = f;
  u32 r = (v.u + 0x7FFFu + ((v.u >> 16) & 1u)) >> 16;
  return (u16)r;
}
__device__ inline float sigf(float x) { return 1.0f / (1.0f + __expf(-x)); }
__device__ inline float tanhf_(float x) {
  float ax = fabsf(x);
  float e = __expf(-2.0f * ax);
  float r = (1.0f - e) / (1.0f + e);
  return copysignf(r, x);
}

// ---- prep kernels ----------------------------------------------------------
// pad+cast rows of [rows, srcCols] fp32 -> [rows, dstCols] bf16 (pad zeros)
__global__ void pad_cast(const float* __restrict__ src, u16* __restrict__ dst,
                         int srcCols, int dstCols, int rows) {
  int idx = blockIdx.x * 256 + threadIdx.x;
  if (idx >= rows * dstCols) return;
  int r = idx / dstCols, c = idx % dstCols;
  float v = (c < srcCols) ? src[r * srcCols + c] : 0.f;
  dst[idx] = f2bf(v);
}

// src [srcK, srcN] row-major fp32 -> dst [Npad, Kpad] bf16 (B^T, zero pad)
__global__ void transpose_cast(const float* __restrict__ src, u16* __restrict__ dst,
                               int srcK, int srcN, int Kpad, int total) {
  int idx = blockIdx.x * 256 + threadIdx.x;
  if (idx >= total) return;
  int n = idx / Kpad, k = idx % Kpad;
  float v = (k < srcK && n < srcN) ? src[k * srcN + n] : 0.f;
  dst[idx] = f2bf(v);
}

// Build combined layer-2/3 weights, K-major: dst [4096][832] bf16.
// Rows (np): cell = np>>11 (0:t-cell x=ht, 1:a-cell x=ha); n = np&2047 in [0,2000):
// gate g = n/400 in {i,f1,f2,o,u}, j = n%400. Cols (r): r<400 -> ht coeff, else ha.
__global__ void build_cell_B(const float* __restrict__ WxT, const float* __restrict__ UT,
                             const float* __restrict__ WxA, const float* __restrict__ UA,
                             u16* __restrict__ dst) {
  int idx = blockIdx.x * 256 + threadIdx.x;
  if (idx >= 4096 * 832) return;
  int np = idx / 832, r = idx % 832;
  int cell = np >> 11;
  int n = np & 2047;
  float v = 0.f;
  if (n < 2000 && r < 800) {
    int g = n / 400, j = n % 400;
    bool htside = (r < 400);
    int rr = htside ? r : r - 400;
    const float* Wx = cell ? WxA : WxT;
    const float* U  = cell ? UA  : UT;
    int gc = (g == 0) ? j : (g <= 2) ? 400 + j : (g == 3) ? 800 + j : 1200 + j;
    float wx = Wx[rr * 1600 + gc];
    float uu = U [rr * 1600 + gc];
    if (cell == 0) { // x = ht = h1
      if (htside) v = (g == 2) ? wx : wx + uu;   // f2: Wxf only
      else        v = (g == 1) ? 0.f : uu;        // f1: no ha term
    } else {          // x = ha = h2
      if (htside) v = (g == 2) ? 0.f : uu;
      else        v = (g == 1) ? wx : wx + uu;
    }
  }
  dst[idx] = f2bf(v);
}

// Projection weights, K-major: dst [256][832] bf16. n<55: W_cur; 55..106: W_ac (ht3 only);
// 107..161: W_ap (ha3 only).
__global__ void build_proj_B(const float* __restrict__ Wcur, const float* __restrict__ Wac,
                             const float* __restrict__ Wap, u16* __restrict__ dst) {
  int idx = blockIdx.x * 256 + threadIdx.x;
  if (idx >= 256 * 832) return;
  int n = idx / 832, r = idx % 832;
  float v = 0.f;
  if (r < 800) {
    if (n < 55) v = Wcur[r * 55 + n];
    else if (n < 107) { if (r < 400) v = Wac[r * 52 + (n - 55)]; }
    else if (n < 162) { if (r >= 400) v = Wap[(r - 400) * 55 + (n - 107)]; }
  }
  dst[idx] = f2bf(v);
}

// ---- GEMM: C[8192, N] = A[8192, K] * B^T[N, K], bf16 in / fp32 out ---------
// 128x128 tile, BK=64, 256 threads (4 waves 2x2), mfma_f32_16x16x32_bf16.
// LDS tiles [dim][64] bf16 with XOR swizzle byte ^= ((row&7)<<4) (G4 fix).
__global__ __launch_bounds__(256) void gemm_bf16(
    const u16* __restrict__ A, const u16* __restrict__ Bt,
    float* __restrict__ C, int K, int ldc) {
  __shared__ u16 As[128 * 64];
  __shared__ u16 Bs[128 * 64];
  const int tid = threadIdx.x;
  const int lane = tid & 63;
  const int wid = tid >> 6;
  const int wm = (wid >> 1) << 6;
  const int wn = (wid & 1) << 6;
  const int m0 = blockIdx.y * 128;
  const int n0 = blockIdx.x * 128;

  f32x4 acc[4][4];
#pragma unroll
  for (int i = 0; i < 4; ++i)
#pragma unroll
    for (int j = 0; j < 4; ++j) acc[i][j] = (f32x4){0.f, 0.f, 0.f, 0.f};

  const int nkt = K >> 6;
  const u16* Ag = A + (size_t)m0 * K;
  const u16* Bg = Bt + (size_t)n0 * K;

  // staging: each thread 4 chunks of 8 bf16 for A and B
  const int e = tid * 8;
  const int sr = e >> 6;        // 0..31; chunk c adds 32 rows (32&7==0 so XOR const)
  const int sc = e & 63;
  const int wbyte = sr * 128 + ((sc * 2) ^ ((sr & 7) << 4));

  const int kq = (lane >> 4) << 3;  // k sub-offset 0/8/16/24
  const int rrow = lane & 15;

  i32x4 ra[4], rb[4];
#pragma unroll
  for (int c = 0; c < 4; ++c) {
    ra[c] = *(const i32x4*)(Ag + (size_t)(sr + c * 32) * K + sc);
    rb[c] = *(const i32x4*)(Bg + (size_t)(sr + c * 32) * K + sc);
  }

  for (int kt = 0; kt < nkt; ++kt) {
    __syncthreads();  // prev compute done -> safe to overwrite LDS
#pragma unroll
    for (int c = 0; c < 4; ++c) {
      *(i32x4*)((char*)As + wbyte + c * 4096) = ra[c];
      *(i32x4*)((char*)Bs + wbyte + c * 4096) = rb[c];
    }
    __syncthreads();
    if (kt + 1 < nkt) {  // prefetch next tile; overlaps MFMA below
      const u16* Agk = Ag + (kt + 1) * 64;
      const u16* Bgk = Bg + (kt + 1) * 64;
#pragma unroll
      for (int c = 0; c < 4; ++c) {
        ra[c] = *(const i32x4*)(Agk + (size_t)(sr + c * 32) * K + sc);
        rb[c] = *(const i32x4*)(Bgk + (size_t)(sr + c * 32) * K + sc);
      }
    }
#pragma unroll
    for (int half = 0; half < 2; ++half) {
      const int kk = half * 32 + kq;
      s16x8 af[4], bf4[4];
#pragma unroll
      for (int f = 0; f < 4; ++f) {
        int ar = wm + f * 16 + rrow;
        af[f] = *(const s16x8*)((const char*)As + ar * 128 + ((kk * 2) ^ ((ar & 7) << 4)));
        int br = wn + f * 16 + rrow;
        bf4[f] = *(const s16x8*)((const char*)Bs + br * 128 + ((kk * 2) ^ ((br & 7) << 4)));
      }
#pragma unroll
      for (int i = 0; i < 4; ++i)
#pragma unroll
        for (int j = 0; j < 4; ++j)
          acc[i][j] = __builtin_amdgcn_mfma_f32_16x16x32_bf16(af[i], bf4[j], acc[i][j], 0, 0, 0);
    }
  }
  __syncthreads();

  // C/D layout (m89-verified): col = lane&15, row = (lane>>4)*4 + reg
  const int crow0 = m0 + wm + ((lane >> 4) << 2);
  const int ccol0 = n0 + wn + (lane & 15);
#pragma unroll
  for (int i = 0; i < 4; ++i)
#pragma unroll
    for (int j = 0; j < 4; ++j)
#pragma unroll
      for (int r = 0; r < 4; ++r)
        C[(size_t)(crow0 + i * 16 + r) * ldc + (ccol0 + j * 16)] = acc[i][j][r];
}

// ---- epilogues -------------------------------------------------------------
// layer1: gates i,f,o,u at cols 0/400/800/1200; children zero -> c = i*u
__global__ void ep1(const float* __restrict__ G, const float* __restrict__ b,
                    u16* __restrict__ Aout, float* __restrict__ Cout, int colbase) {
  int j = blockIdx.x * 256 + threadIdx.x;
  int t = blockIdx.y;
  if (j >= 400) return;
  const float* g = G + (size_t)t * GLD;
  float ip = g[j] + b[j];
  float op = g[800 + j] + b[800 + j];
  float up = g[1200 + j] + b[1200 + j];
  float c = sigf(ip) * tanhf_(up);
  float h = sigf(op) * tanhf_(c);
  Aout[(size_t)t * 832 + colbase + j] = f2bf(h);
  Cout[(size_t)t * 400 + j] = c;
}

// layer2/3: combined gate cols i,f1,f2,o,u at 0/400/800/1200/1600
__global__ void ep2(const float* __restrict__ G, const float* __restrict__ b,
                    const float* __restrict__ C1, const float* __restrict__ C2,
                    u16* __restrict__ Aout, float* __restrict__ Cout, int colbase) {
  int j = blockIdx.x * 256 + threadIdx.x;
  int t = blockIdx.y;
  if (j >= 400) return;
  const float* g = G + (size_t)t * GLD;
  float ip  = g[j]        + b[j];
  float f1p = g[400 + j]  + b[400 + j];
  float f2p = g[800 + j]  + b[400 + j];
  float op  = g[1200 + j] + b[800 + j];
  float up  = g[1600 + j] + b[1200 + j];
  size_t cj = (size_t)t * 400 + j;
  float c = sigf(ip) * tanhf_(up) + sigf(f1p) * C1[cj] + sigf(f2p) * C2[cj];
  float h = sigf(op) * tanhf_(c);
  Aout[(size_t)t * 832 + colbase + j] = f2bf(h);
  Cout[cj] = c;
}

__global__ void ep_out(const float* __restrict__ G,
                       const float* __restrict__ bcur, const float* __restrict__ bac,
                       const float* __restrict__ bap, float* __restrict__ out) {
  int j = blockIdx.x * 256 + threadIdx.x;
  int t = blockIdx.y;
  if (j >= 162) return;
  float v = G[(size_t)t * GLD + j];
  if (j < 55)       out[t * 55 + j] = v + bcur[j];
  else if (j < 107) out[450560 + t * 52 + (j - 55)] = v + bac[j - 55];
  else              out[876544 + t * 55 + (j - 107)] = v + bap[j - 107];
}

// ---- launch ----------------------------------------------------------------
extern "C" void kernel_launch(void* const* d_in, const int* in_sizes, int n_in,
                              void* d_out, int out_size, void* d_ws, size_t ws_size,
                              hipStream_t stream) {
  const float* x_temp = (const float*)d_in[0];
  const float* x_air  = (const float*)d_in[1];
  const float* Wx_t1  = (const float*)d_in[2];
  const float* b_t1   = (const float*)d_in[4];
  const float* Wx_t2  = (const float*)d_in[5];
  const float* U_t2   = (const float*)d_in[6];
  const float* b_t2   = (const float*)d_in[7];
  const float* Wx_t3  = (const float*)d_in[8];
  const float* U_t3   = (const float*)d_in[9];
  const float* b_t3   = (const float*)d_in[10];
  const float* Wx_a1  = (const float*)d_in[11];
  const float* b_a1   = (const float*)d_in[13];
  const float* Wx_a2  = (const float*)d_in[14];
  const float* U_a2   = (const float*)d_in[15];
  const float* b_a2   = (const float*)d_in[16];
  const float* Wx_a3  = (const float*)d_in[17];
  const float* U_a3   = (const float*)d_in[18];
  const float* b_a3   = (const float*)d_in[19];
  const float* W_cur  = (const float*)d_in[20];
  const float* b_cur  = (const float*)d_in[21];
  const float* W_ac   = (const float*)d_in[22];
  const float* b_ac   = (const float*)d_in[23];
  const float* W_ap   = (const float*)d_in[24];
  const float* b_ap   = (const float*)d_in[25];

  char* ws = (char*)d_ws;
  u16*   A0t = (u16*)(ws + 0);          // [8192][64]
  u16*   A0a = (u16*)(ws + 1048576);
  u16*   B1t = (u16*)(ws + 2097152);    // [1664][64]
  u16*   B1a = (u16*)(ws + 2310144);
  u16*   Bp  = (u16*)(ws + 2523136);    // [256][832]
  u16*   A1  = (u16*)(ws + 2949120);    // [8192][832]  (ht|ha|pad)
  u16*   A2  = (u16*)(ws + 16580608);
  u16*   A3  = (u16*)(ws + 30212096);
  float* Ct  = (float*)(ws + 43843584); // [8192][400]
  float* Ca  = (float*)(ws + 56950784);
  float* C2t = (float*)(ws + 70057984);
  float* C2a = (float*)(ws + 83165184);
  u16*   B2  = (u16*)(ws + 96272384);   // [4096][832] (cell t rows 0..2047, cell a 2048..)
  u16*   B3  = (u16*)(ws + 103088128);
  float* G   = (float*)(ws + 109903872);// [8192][2048] fp32
  float* out = (float*)d_out;

  // zero A1..A3 (contiguous) so K-pad cols are 0
  hipMemsetAsync(A1, 0, 3ULL * 13631488ULL, stream);

  pad_cast<<<2048, 256, 0, stream>>>(x_temp, A0t, 55, 64, 8192);
  pad_cast<<<2048, 256, 0, stream>>>(x_air,  A0a, 55, 64, 8192);
  transpose_cast<<<416, 256, 0, stream>>>(Wx_t1, B1t, 55, 1600, 64, 1664 * 64);
  transpose_cast<<<416, 256, 0, stream>>>(Wx_a1, B1a, 55, 1600, 64, 1664 * 64);
  build_cell_B<<<13312, 256, 0, stream>>>(Wx_t2, U_t2, Wx_a2, U_a2, B2);
  build_cell_B<<<13312, 256, 0, stream>>>(Wx_t3, U_t3, Wx_a3, U_a3, B3);
  build_proj_B<<<832, 256, 0, stream>>>(W_cur, W_ac, W_ap, Bp);

  dim3 blk(256);
  // layer 1
  gemm_bf16<<<dim3(13, 64), blk, 0, stream>>>(A0t, B1t, G, 64, GLD);
  ep1<<<dim3(2, 8192), blk, 0, stream>>>(G, b_t1, A1, Ct, 0);
  gemm_bf16<<<dim3(13, 64), blk, 0, stream>>>(A0a, B1a, G, 64, GLD);
  ep1<<<dim3(2, 8192), blk, 0, stream>>>(G, b_a1, A1, Ca, 400);
  // layer 2
  gemm_bf16<<<dim3(16, 64), blk, 0, stream>>>(A1, B2, G, 832, GLD);
  ep2<<<dim3(2, 8192), blk, 0, stream>>>(G, b_t2, Ct, Ca, A2, C2t, 0);
  gemm_bf16<<<dim3(16, 64), blk, 0, stream>>>(A1, B2 + 2048 * 832, G, 832, GLD);
  ep2<<<dim3(2, 8192), blk, 0, stream>>>(G, b_a2, Ct, Ca, A2, C2a, 400);
  // layer 3
  gemm_bf16<<<dim3(16, 64), blk, 0, stream>>>(A2, B3, G, 832, GLD);
  ep2<<<dim3(2, 8192), blk, 0, stream>>>(G, b_t3, C2t, C2a, A3, Ct, 0);
  gemm_bf16<<<dim3(16, 64), blk, 0, stream>>>(A2, B3 + 2048 * 832, G, 832, GLD);
  ep2<<<dim3(2, 8192), blk, 0, stream>>>(G, b_a3, C2t, C2a, A3, Ca, 400);
  // projections
  gemm_bf16<<<dim3(2, 64), blk, 0, stream>>>(A3, Bp, G, 832, GLD);
  ep_out<<<dim3(1, 8192), blk, 0, stream>>>(G, b_cur, b_ac, b_ap, out);
}

// Round 3
// 417.655 us; speedup vs baseline: 1.1440x; 1.1440x over previous
//
#include <hip/hip_runtime.h>
#include <hip/hip_bf16.h>

typedef unsigned short u16;
typedef unsigned int u32;
typedef unsigned long long u64;
typedef __attribute__((ext_vector_type(4))) float f32x4;
typedef __attribute__((ext_vector_type(8))) short s16x8;

__device__ inline u16 f2bf(float f) {
  union { float f; u32 u; } v; v.f = f;
  u32 r = (v.u + 0x7FFFu + ((v.u >> 16) & 1u)) >> 16;
  return (u16)r;
}
__device__ inline float bf2f(u16 h) { return __uint_as_float((u32)h << 16); }
__device__ inline float sigf(float x) { return 1.0f / (1.0f + __expf(-x)); }
__device__ inline float tanhf_(float x) {
  float ax = fabsf(x);
  float e = __expf(-2.0f * ax);
  float r = (1.0f - e) / (1.0f + e);
  return copysignf(r, x);
}
__device__ inline f32x4 ld4bf(const u16* p) {
  u64 v = *(const u64*)p;
  f32x4 r;
  r.x = __uint_as_float((u32)(v & 0xFFFFu) << 16);
  r.y = __uint_as_float((u32)((v >> 16) & 0xFFFFu) << 16);
  r.z = __uint_as_float((u32)((v >> 32) & 0xFFFFu) << 16);
  r.w = __uint_as_float((u32)((v >> 48) & 0xFFFFu) << 16);
  return r;
}
__device__ inline void gload16(const u16* g, u16* l) {
  __builtin_amdgcn_global_load_lds(
      (const __attribute__((address_space(1))) void*)(g),
      (__attribute__((address_space(3))) void*)(l), 16, 0, 0);
}

#define GLD 4096  // G row stride (u16 / bf16)

// ---- prep kernels ----------------------------------------------------------
__global__ void zero_pads(u16* __restrict__ A1, u16* __restrict__ A2,
                          u16* __restrict__ A3) {
  int idx = blockIdx.x * 256 + threadIdx.x;  // 3 * 8192 * 8 quads
  if (idx >= 196608) return;
  int b = idx / 65536, r = idx % 65536;
  int t = r / 8, q = r % 8;
  u16* A = (b == 0) ? A1 : (b == 1) ? A2 : A3;
  *(u64*)(A + (size_t)t * 832 + 800 + q * 4) = 0ULL;
}

__global__ void pad_cast(const float* __restrict__ src, u16* __restrict__ dst,
                         int srcCols, int dstCols, int rows) {
  int idx = blockIdx.x * 256 + threadIdx.x;
  if (idx >= rows * dstCols) return;
  int r = idx / dstCols, c = idx % dstCols;
  float v = (c < srcCols) ? src[r * srcCols + c] : 0.f;
  dst[idx] = f2bf(v);
}

// src [srcK, srcN] fp32 -> dst [N=1664, Kpad=64] bf16 (B^T).  Lanes along n
// (coalesced src reads); writes scattered (dst is L2-resident, 213 KB).
__global__ void transpose_cast(const float* __restrict__ src, u16* __restrict__ dst,
                               int srcK, int srcN) {
  int idx = blockIdx.x * 256 + threadIdx.x;
  if (idx >= 64 * 1664) return;
  int k = idx / 1664, n = idx % 1664;
  float v = (k < srcK && n < srcN) ? src[k * srcN + n] : 0.f;
  dst[n * 64 + k] = f2bf(v);
}

// Combined layer-2/3 weights, K-major: dst [4096][832] bf16.
// np: cell=np>>11 (0: x=ht, 1: x=ha); n=np&2047 in [0,2000): g=n/400 {i,f1,f2,o,u},
// j=n%400. col r: r<400 ht coeff else ha.  Lanes along np (coalesced Wx/U reads).
__global__ void build_cell_B(const float* __restrict__ WxT, const float* __restrict__ UT,
                             const float* __restrict__ WxA, const float* __restrict__ UA,
                             u16* __restrict__ dst) {
  int idx = blockIdx.x * 256 + threadIdx.x;
  if (idx >= 4096 * 832) return;
  int r = idx / 4096, np = idx % 4096;
  int cell = np >> 11;
  int n = np & 2047;
  float v = 0.f;
  if (n < 2000 && r < 800) {
    int g = n / 400, j = n % 400;
    bool htside = (r < 400);
    int rr = htside ? r : r - 400;
    const float* Wx = cell ? WxA : WxT;
    const float* U  = cell ? UA  : UT;
    int gc = (g == 0) ? j : (g <= 2) ? 400 + j : (g == 3) ? 800 + j : 1200 + j;
    float wx = Wx[rr * 1600 + gc];
    float uu = U [rr * 1600 + gc];
    if (cell == 0) { // x = ht = h1
      if (htside) v = (g == 2) ? wx : wx + uu;   // f2 col: Wxf only
      else        v = (g == 1) ? 0.f : uu;        // f1 col: no ha term
    } else {          // x = ha = h2
      if (htside) v = (g == 2) ? 0.f : uu;
      else        v = (g == 1) ? wx : wx + uu;
    }
  }
  dst[(size_t)np * 832 + r] = f2bf(v);
}

__global__ void build_proj_B(const float* __restrict__ Wcur, const float* __restrict__ Wac,
                             const float* __restrict__ Wap, u16* __restrict__ dst) {
  int idx = blockIdx.x * 256 + threadIdx.x;
  if (idx >= 256 * 832) return;
  int n = idx / 832, r = idx % 832;
  float v = 0.f;
  if (r < 800) {
    if (n < 55) v = Wcur[r * 55 + n];
    else if (n < 107) { if (r < 400) v = Wac[r * 52 + (n - 55)]; }
    else if (n < 162) { if (r >= 400) v = Wap[(r - 400) * 55 + (n - 107)]; }
  }
  dst[idx] = f2bf(v);
}

// ---- GEMM: C[8192, N] = A[8192, K] * B^T[N, K], bf16 in / bf16 out ---------
// 128x128 tile, BK=64, 4 waves 2x2, mfma_f32_16x16x32_bf16.
// Staging: global_load_lds width=16, linear LDS dest + pre-swizzled global
// source (rule 21); read-side XOR swizzle byte ^= ((row&7)<<4) (round-2-verified).
__global__ __launch_bounds__(256) void gemm_lds(
    const u16* __restrict__ A, const u16* __restrict__ Bt,
    u16* __restrict__ C, int K, int ldc) {
  __shared__ u16 As[128 * 64];
  __shared__ u16 Bs[128 * 64];
  const int tid = threadIdx.x;
  const int lane = tid & 63;
  const int wid = tid >> 6;

  // bijective XCD swizzle (all grids have nwg % 8 == 0)
  const int nwg = gridDim.x * gridDim.y;
  const int bid = blockIdx.y * gridDim.x + blockIdx.x;
  const int swz = (bid & 7) * (nwg >> 3) + (bid >> 3);
  const int m0 = (swz / gridDim.x) * 128;
  const int n0 = (swz % gridDim.x) * 128;

  const int wm = (wid >> 1) << 6;
  const int wn = (wid & 1) << 6;

  f32x4 acc[4][4];
#pragma unroll
  for (int i = 0; i < 4; ++i)
#pragma unroll
    for (int j = 0; j < 4; ++j) acc[i][j] = (f32x4){0.f, 0.f, 0.f, 0.f};

  const int nkt = K >> 6;
  const int l8 = lane >> 3, lb = lane & 7;
  const int scol = (lb ^ l8) << 3;  // swizzled source col (u16)
  const u16* gA = A + (size_t)(m0 + wid * 8 + l8) * K + scol;
  const u16* gB = Bt + (size_t)(n0 + wid * 8 + l8) * K + scol;
  u16* lA = As + wid * 8 * 64;  // wave-uniform LDS bases
  u16* lB = Bs + wid * 8 * 64;

  const int kq = (lane >> 4) << 3;
  const int rrow = lane & 15;

  for (int kt = 0; kt < nkt; ++kt) {
    __syncthreads();  // previous compute done -> safe to overwrite LDS
    const u16* pa = gA + kt * 64;
    const u16* pb = gB + kt * 64;
#pragma unroll
    for (int c = 0; c < 4; ++c) {
      gload16(pa + (size_t)(c * 32) * K, lA + c * 2048);
      gload16(pb + (size_t)(c * 32) * K, lB + c * 2048);
    }
    __syncthreads();  // compiler drains vmcnt(0) before barrier -> tile ready
#pragma unroll
    for (int half = 0; half < 2; ++half) {
      const int kk = half * 32 + kq;
      s16x8 af[4], bfr[4];
#pragma unroll
      for (int f = 0; f < 4; ++f) {
        int ar = wm + f * 16 + rrow;
        af[f] = *(const s16x8*)((const char*)As + ar * 128 + ((kk * 2) ^ ((ar & 7) << 4)));
        int br = wn + f * 16 + rrow;
        bfr[f] = *(const s16x8*)((const char*)Bs + br * 128 + ((kk * 2) ^ ((br & 7) << 4)));
      }
#pragma unroll
      for (int i = 0; i < 4; ++i)
#pragma unroll
        for (int j = 0; j < 4; ++j)
          acc[i][j] = __builtin_amdgcn_mfma_f32_16x16x32_bf16(af[i], bfr[j], acc[i][j], 0, 0, 0);
    }
  }

  // C/D layout (m89-verified): col = lane&15, row = (lane>>4)*4 + reg
  const int crow0 = m0 + wm + ((lane >> 4) << 2);
  const int ccol0 = n0 + wn + rrow;
#pragma unroll
  for (int i = 0; i < 4; ++i)
#pragma unroll
    for (int j = 0; j < 4; ++j)
#pragma unroll
      for (int r = 0; r < 4; ++r)
        C[(size_t)(crow0 + i * 16 + r) * ldc + (ccol0 + j * 16)] = f2bf(acc[i][j][r]);
}

// ---- epilogues (merged t+a cells, 4-wide) ----------------------------------
// layer1: gates i,-,o,u at cols 0/800/1200 (+cell*2048); children zero -> c = i*u
__global__ void ep1(const u16* __restrict__ G,
                    const float* __restrict__ bT, const float* __restrict__ bA,
                    u16* __restrict__ Aout,
                    float* __restrict__ CT, float* __restrict__ CA) {
  int idx = blockIdx.x * 256 + threadIdx.x;
  if (idx >= 8192 * 200) return;
  int t = idx / 200, r = idx % 200;
  int cell = r / 100, j0 = (r % 100) * 4;
  const u16* g = G + (size_t)t * GLD + cell * 2048;
  const float* b = cell ? bA : bT;
  float* Cout = cell ? CA : CT;
  f32x4 ip = ld4bf(g + j0);
  f32x4 op = ld4bf(g + 800 + j0);
  f32x4 up = ld4bf(g + 1200 + j0);
  u64 hv = 0;
  f32x4 cv;
#pragma unroll
  for (int k = 0; k < 4; ++k) {
    int j = j0 + k;
    float c = sigf(ip[k] + b[j]) * tanhf_(up[k] + b[1200 + j]);
    float h = sigf(op[k] + b[800 + j]) * tanhf_(c);
    cv[k] = c;
    hv |= (u64)f2bf(h) << (16 * k);
  }
  *(u64*)(Aout + (size_t)t * 832 + cell * 400 + j0) = hv;
  *(f32x4*)(Cout + (size_t)t * 400 + j0) = cv;
}

// layer2/3: gates i,f1,f2,o,u at cols 0/400/800/1200/1600 (+cell*2048)
__global__ void ep2(const u16* __restrict__ G,
                    const float* __restrict__ bT, const float* __restrict__ bA,
                    const float* __restrict__ C1, const float* __restrict__ C2,
                    u16* __restrict__ Aout,
                    float* __restrict__ CT, float* __restrict__ CA) {
  int idx = blockIdx.x * 256 + threadIdx.x;
  if (idx >= 8192 * 200) return;
  int t = idx / 200, r = idx % 200;
  int cell = r / 100, j0 = (r % 100) * 4;
  const u16* g = G + (size_t)t * GLD + cell * 2048;
  const float* b = cell ? bA : bT;
  float* Cout = cell ? CA : CT;
  f32x4 ip  = ld4bf(g + j0);
  f32x4 f1p = ld4bf(g + 400 + j0);
  f32x4 f2p = ld4bf(g + 800 + j0);
  f32x4 op  = ld4bf(g + 1200 + j0);
  f32x4 up  = ld4bf(g + 1600 + j0);
  f32x4 c1 = *(const f32x4*)(C1 + (size_t)t * 400 + j0);
  f32x4 c2 = *(const f32x4*)(C2 + (size_t)t * 400 + j0);
  u64 hv = 0;
  f32x4 cv;
#pragma unroll
  for (int k = 0; k < 4; ++k) {
    int j = j0 + k;
    float c = sigf(ip[k] + b[j]) * tanhf_(up[k] + b[1200 + j])
            + sigf(f1p[k] + b[400 + j]) * c1[k]
            + sigf(f2p[k] + b[400 + j]) * c2[k];
    float h = sigf(op[k] + b[800 + j]) * tanhf_(c);
    cv[k] = c;
    hv |= (u64)f2bf(h) << (16 * k);
  }
  *(u64*)(Aout + (size_t)t * 832 + cell * 400 + j0) = hv;
  if (Cout) *(f32x4*)(Cout + (size_t)t * 400 + j0) = cv;
}

__global__ void ep_out(const u16* __restrict__ G,
                       const float* __restrict__ bcur, const float* __restrict__ bac,
                       const float* __restrict__ bap, float* __restrict__ out) {
  int idx = blockIdx.x * 256 + threadIdx.x;
  if (idx >= 8192 * 162) return;
  int t = idx / 162, j = idx % 162;
  float v = bf2f(G[(size_t)t * GLD + j]);
  if (j < 55)       out[t * 55 + j] = v + bcur[j];
  else if (j < 107) out[450560 + t * 52 + (j - 55)] = v + bac[j - 55];
  else              out[876544 + t * 55 + (j - 107)] = v + bap[j - 107];
}

// ---- launch ----------------------------------------------------------------
extern "C" void kernel_launch(void* const* d_in, const int* in_sizes, int n_in,
                              void* d_out, int out_size, void* d_ws, size_t ws_size,
                              hipStream_t stream) {
  const float* x_temp = (const float*)d_in[0];
  const float* x_air  = (const float*)d_in[1];
  const float* Wx_t1  = (const float*)d_in[2];
  const float* b_t1   = (const float*)d_in[4];
  const float* Wx_t2  = (const float*)d_in[5];
  const float* U_t2   = (const float*)d_in[6];
  const float* b_t2   = (const float*)d_in[7];
  const float* Wx_t3  = (const float*)d_in[8];
  const float* U_t3   = (const float*)d_in[9];
  const float* b_t3   = (const float*)d_in[10];
  const float* Wx_a1  = (const float*)d_in[11];
  const float* b_a1   = (const float*)d_in[13];
  const float* Wx_a2  = (const float*)d_in[14];
  const float* U_a2   = (const float*)d_in[15];
  const float* b_a2   = (const float*)d_in[16];
  const float* Wx_a3  = (const float*)d_in[17];
  const float* U_a3   = (const float*)d_in[18];
  const float* b_a3   = (const float*)d_in[19];
  const float* W_cur  = (const float*)d_in[20];
  const float* b_cur  = (const float*)d_in[21];
  const float* W_ac   = (const float*)d_in[22];
  const float* b_ac   = (const float*)d_in[23];
  const float* W_ap   = (const float*)d_in[24];
  const float* b_ap   = (const float*)d_in[25];

  char* ws = (char*)d_ws;
  u16*   A0t = (u16*)(ws + 0);          // [8192][64]
  u16*   A0a = (u16*)(ws + 1048576);
  u16*   B1t = (u16*)(ws + 2097152);    // [1664][64]
  u16*   B1a = (u16*)(ws + 2310144);
  u16*   Bp  = (u16*)(ws + 2523136);    // [256][832]
  u16*   A1  = (u16*)(ws + 2949120);    // [8192][832]  (ht|ha|pad)
  u16*   A2  = (u16*)(ws + 16580608);
  u16*   A3  = (u16*)(ws + 30212096);
  float* Ct  = (float*)(ws + 43843584); // [8192][400]
  float* Ca  = (float*)(ws + 56950784);
  float* C2t = (float*)(ws + 70057984);
  float* C2a = (float*)(ws + 83165184);
  u16*   B2  = (u16*)(ws + 96272384);   // [4096][832] (t rows 0..2047, a rows 2048..)
  u16*   B3  = (u16*)(ws + 103088128);
  u16*   G   = (u16*)(ws + 109903872);  // [8192][4096] bf16
  float* out = (float*)d_out;

  dim3 blk(256);
  zero_pads<<<768, blk, 0, stream>>>(A1, A2, A3);
  pad_cast<<<2048, blk, 0, stream>>>(x_temp, A0t, 55, 64, 8192);
  pad_cast<<<2048, blk, 0, stream>>>(x_air,  A0a, 55, 64, 8192);
  transpose_cast<<<416, blk, 0, stream>>>(Wx_t1, B1t, 55, 1600);
  transpose_cast<<<416, blk, 0, stream>>>(Wx_a1, B1a, 55, 1600);
  build_cell_B<<<13312, blk, 0, stream>>>(Wx_t2, U_t2, Wx_a2, U_a2, B2);
  build_cell_B<<<13312, blk, 0, stream>>>(Wx_t3, U_t3, Wx_a3, U_a3, B3);
  build_proj_B<<<832, blk, 0, stream>>>(W_cur, W_ac, W_ap, Bp);

  // layer 1 (two GEMMs, one merged epilogue)
  gemm_lds<<<dim3(13, 64), blk, 0, stream>>>(A0t, B1t, G, 64, GLD);
  gemm_lds<<<dim3(13, 64), blk, 0, stream>>>(A0a, B1a, G + 2048, 64, GLD);
  ep1<<<6400, blk, 0, stream>>>(G, b_t1, b_a1, A1, Ct, Ca);
  // layer 2 (one merged GEMM)
  gemm_lds<<<dim3(32, 64), blk, 0, stream>>>(A1, B2, G, 832, GLD);
  ep2<<<6400, blk, 0, stream>>>(G, b_t2, b_a2, Ct, Ca, A2, C2t, C2a);
  // layer 3 (c outputs dead -> skip)
  gemm_lds<<<dim3(32, 64), blk, 0, stream>>>(A2, B3, G, 832, GLD);
  ep2<<<6400, blk, 0, stream>>>(G, b_t3, b_a3, C2t, C2a, A3, nullptr, nullptr);
  // projections
  gemm_lds<<<dim3(2, 64), blk, 0, stream>>>(A3, Bp, G, 832, GLD);
  ep_out<<<5184, blk, 0, stream>>>(G, b_cur, b_ac, b_ap, out);
}

// Round 4
// 407.219 us; speedup vs baseline: 1.1733x; 1.0256x over previous
//
#include <hip/hip_runtime.h>
#include <hip/hip_bf16.h>

typedef unsigned short u16;
typedef unsigned int u32;
typedef unsigned long long u64;
typedef __attribute__((ext_vector_type(4))) float f32x4;
typedef __attribute__((ext_vector_type(8))) short s16x8;

__device__ inline u16 f2bf(float f) {
  union { float f; u32 u; } v; v.f = f;
  u32 r = (v.u + 0x7FFFu + ((v.u >> 16) & 1u)) >> 16;
  return (u16)r;
}
__device__ inline float bf2f(u16 h) { return __uint_as_float((u32)h << 16); }
__device__ inline float sigf(float x) { return 1.0f / (1.0f + __expf(-x)); }
__device__ inline float tanhf_(float x) {
  float ax = fabsf(x);
  float e = __expf(-2.0f * ax);
  float r = (1.0f - e) / (1.0f + e);
  return copysignf(r, x);
}
__device__ inline f32x4 ld4bf(const u16* p) {
  u64 v = *(const u64*)p;
  f32x4 r;
  r.x = __uint_as_float((u32)(v & 0xFFFFu) << 16);
  r.y = __uint_as_float((u32)((v >> 16) & 0xFFFFu) << 16);
  r.z = __uint_as_float((u32)((v >> 32) & 0xFFFFu) << 16);
  r.w = __uint_as_float((u32)((v >> 48) & 0xFFFFu) << 16);
  return r;
}
__device__ inline void gload16(const u16* g, u16* l) {
  __builtin_amdgcn_global_load_lds(
      (const __attribute__((address_space(1))) void*)(g),
      (__attribute__((address_space(3))) void*)(l), 16, 0, 0);
}

#define GLD 4096  // G row stride (u16 / bf16)

// ---- prep kernels ----------------------------------------------------------
__global__ void zero_pads(u16* __restrict__ A1, u16* __restrict__ A2,
                          u16* __restrict__ A3) {
  int idx = blockIdx.x * 256 + threadIdx.x;  // 3 * 8192 * 8 quads
  if (idx >= 196608) return;
  int b = idx / 65536, r = idx % 65536;
  int t = r / 8, q = r % 8;
  u16* A = (b == 0) ? A1 : (b == 1) ? A2 : A3;
  *(u64*)(A + (size_t)t * 832 + 800 + q * 4) = 0ULL;
}

__global__ void pad_cast(const float* __restrict__ src, u16* __restrict__ dst,
                         int srcCols, int dstCols, int rows) {
  int idx = blockIdx.x * 256 + threadIdx.x;
  if (idx >= rows * dstCols) return;
  int r = idx / dstCols, c = idx % dstCols;
  float v = (c < srcCols) ? src[r * srcCols + c] : 0.f;
  dst[idx] = f2bf(v);
}

__global__ void transpose_cast(const float* __restrict__ src, u16* __restrict__ dst,
                               int srcK, int srcN) {
  int idx = blockIdx.x * 256 + threadIdx.x;
  if (idx >= 64 * 1664) return;
  int k = idx / 1664, n = idx % 1664;
  float v = (k < srcK && n < srcN) ? src[k * srcN + n] : 0.f;
  dst[n * 64 + k] = f2bf(v);
}

// Combined layer-2/3 weights, K-major: dst [4096][832] bf16, LDS-tiled so both
// the Wx/U reads (lanes along np -> consecutive gc) and the dst writes (lanes
// along r -> consecutive) are coalesced.
// np: cell=np>>11 (0: x=ht, 1: x=ha); n=np&2047 in [0,2000): g=n/400 {i,f1,f2,o,u},
// j=n%400. col r: r<400 ht coeff else ha.
__global__ __launch_bounds__(256) void build_cell_B(
    const float* __restrict__ WxT, const float* __restrict__ UT,
    const float* __restrict__ WxA, const float* __restrict__ UA,
    u16* __restrict__ dst) {
  __shared__ float tile[64][65];
  const int np0 = blockIdx.x * 64;
  const int r0 = blockIdx.y * 64;
  const int tx = threadIdx.x & 63, ty = threadIdx.x >> 6;

  const int np = np0 + tx;
  const int cell = np >> 11;
  const int n = np & 2047;
  const float* Wx = cell ? WxA : WxT;
  const float* U  = cell ? UA  : UT;
  int g = 0, j = 0, gc = 0;
  if (n < 2000) {
    g = n / 400; j = n % 400;
    gc = (g == 0) ? j : (g <= 2) ? 400 + j : (g == 3) ? 800 + j : 1200 + j;
  }
#pragma unroll
  for (int it = 0; it < 16; ++it) {
    int r = r0 + it * 4 + ty;
    float v = 0.f;
    if (n < 2000 && r < 800) {
      bool htside = (r < 400);
      int rr = htside ? r : r - 400;
      float wx = Wx[rr * 1600 + gc];
      float uu = U [rr * 1600 + gc];
      if (cell == 0) { // x = ht = h1
        if (htside) v = (g == 2) ? wx : wx + uu;   // f2 col: Wxf only
        else        v = (g == 1) ? 0.f : uu;        // f1 col: no ha term
      } else {          // x = ha = h2
        if (htside) v = (g == 2) ? 0.f : uu;
        else        v = (g == 1) ? wx : wx + uu;
      }
    }
    tile[tx][it * 4 + ty] = v;
  }
  __syncthreads();
#pragma unroll
  for (int it = 0; it < 16; ++it) {
    int npw = np0 + it * 4 + ty;
    dst[(size_t)npw * 832 + r0 + tx] = f2bf(tile[it * 4 + ty][tx]);
  }
}

__global__ void build_proj_B(const float* __restrict__ Wcur, const float* __restrict__ Wac,
                             const float* __restrict__ Wap, u16* __restrict__ dst) {
  int idx = blockIdx.x * 256 + threadIdx.x;
  if (idx >= 256 * 832) return;
  int n = idx / 832, r = idx % 832;
  float v = 0.f;
  if (r < 800) {
    if (n < 55) v = Wcur[r * 55 + n];
    else if (n < 107) { if (r < 400) v = Wac[r * 52 + (n - 55)]; }
    else if (n < 162) { if (r >= 400) v = Wap[(r - 400) * 55 + (n - 107)]; }
  }
  dst[idx] = f2bf(v);
}

// ---- GEMM (small shapes): 128x128 tile, 2-phase, round-2/3-verified --------
__global__ __launch_bounds__(256) void gemm_lds(
    const u16* __restrict__ A, const u16* __restrict__ Bt,
    u16* __restrict__ C, int K, int ldc) {
  __shared__ u16 As[128 * 64];
  __shared__ u16 Bs[128 * 64];
  const int tid = threadIdx.x;
  const int lane = tid & 63;
  const int wid = tid >> 6;

  const int nwg = gridDim.x * gridDim.y;
  const int bid = blockIdx.y * gridDim.x + blockIdx.x;
  const int swz = (bid & 7) * (nwg >> 3) + (bid >> 3);
  const int m0 = (swz / gridDim.x) * 128;
  const int n0 = (swz % gridDim.x) * 128;

  const int wm = (wid >> 1) << 6;
  const int wn = (wid & 1) << 6;

  f32x4 acc[4][4];
#pragma unroll
  for (int i = 0; i < 4; ++i)
#pragma unroll
    for (int j = 0; j < 4; ++j) acc[i][j] = (f32x4){0.f, 0.f, 0.f, 0.f};

  const int nkt = K >> 6;
  const int l8 = lane >> 3, lb = lane & 7;
  const int scol = (lb ^ l8) << 3;
  const u16* gA = A + (size_t)(m0 + wid * 8 + l8) * K + scol;
  const u16* gB = Bt + (size_t)(n0 + wid * 8 + l8) * K + scol;
  u16* lA = As + wid * 8 * 64;
  u16* lB = Bs + wid * 8 * 64;

  const int kq = (lane >> 4) << 3;
  const int rrow = lane & 15;

  for (int kt = 0; kt < nkt; ++kt) {
    __syncthreads();
    const u16* pa = gA + kt * 64;
    const u16* pb = gB + kt * 64;
#pragma unroll
    for (int c = 0; c < 4; ++c) {
      gload16(pa + (size_t)(c * 32) * K, lA + c * 2048);
      gload16(pb + (size_t)(c * 32) * K, lB + c * 2048);
    }
    __syncthreads();
#pragma unroll
    for (int half = 0; half < 2; ++half) {
      const int kk = half * 32 + kq;
      s16x8 af[4], bfr[4];
#pragma unroll
      for (int f = 0; f < 4; ++f) {
        int ar = wm + f * 16 + rrow;
        af[f] = *(const s16x8*)((const char*)As + ar * 128 + ((kk * 2) ^ ((ar & 7) << 4)));
        int br = wn + f * 16 + rrow;
        bfr[f] = *(const s16x8*)((const char*)Bs + br * 128 + ((kk * 2) ^ ((br & 7) << 4)));
      }
#pragma unroll
      for (int i = 0; i < 4; ++i)
#pragma unroll
        for (int j = 0; j < 4; ++j)
          acc[i][j] = __builtin_amdgcn_mfma_f32_16x16x32_bf16(af[i], bfr[j], acc[i][j], 0, 0, 0);
    }
  }

  const int crow0 = m0 + wm + ((lane >> 4) << 2);
  const int ccol0 = n0 + wn + rrow;
#pragma unroll
  for (int i = 0; i < 4; ++i)
#pragma unroll
    for (int j = 0; j < 4; ++j)
#pragma unroll
      for (int r = 0; r < 4; ++r)
        C[(size_t)(crow0 + i * 16 + r) * ldc + (ccol0 + j * 16)] = f2bf(acc[i][j][r]);
}

// ---- GEMM (big shapes): 256x128 tile, 3-buffer pipeline, counted vmcnt -----
// K hardcoded 832 (13 K-tiles). 512 threads = 8 waves (4M x 2N), per-wave
// 64x64 out. Stage tile k+2 while computing tile k (distinct buffers);
// s_waitcnt vmcnt(12) = 6 loads/thread/tile x 2 tiles in flight, never 0 in
// steady state (T3+T4). Raw s_barrier; sched_barrier(0) pins ds_reads.
#define PK 832
#define PNKT 13
#define ABY 32768   // A tile bytes: 256*64*2
#define BBY 16384   // B tile bytes: 128*64*2
#define BUFB 49152

__global__ __launch_bounds__(512, 2) void gemm_pipe(
    const u16* __restrict__ A, const u16* __restrict__ Bt,
    u16* __restrict__ C, int ldc) {
  __shared__ char sm[3 * BUFB];  // 144 KiB
  const int tid = threadIdx.x;
  const int lane = tid & 63;
  const int wid = tid >> 6;

  const int nwg = gridDim.x * gridDim.y;
  const int bid = blockIdx.y * gridDim.x + blockIdx.x;
  const int swz = (bid & 7) * (nwg >> 3) + (bid >> 3);
  const int m0 = (swz / gridDim.x) * 256;
  const int n0 = (swz % gridDim.x) * 128;

  const int wr = wid >> 1;   // 0..3 (M)
  const int wc = wid & 1;    // 0..1 (N)

  f32x4 acc[4][4];
#pragma unroll
  for (int i = 0; i < 4; ++i)
#pragma unroll
    for (int j = 0; j < 4; ++j) acc[i][j] = (f32x4){0.f, 0.f, 0.f, 0.f};

  // staging: linear LDS dest + pre-swizzled global source (rule 21)
  const int q = lane >> 3, lb = lane & 7;
  const int scol = (lb ^ q) << 3;
  const u16* gA = A + (size_t)(m0 + wid * 8 + q) * PK + scol;
  const u16* gB = Bt + (size_t)(n0 + wid * 8 + q) * PK + scol;
  const int wrow = wid * 8;  // wave-uniform LDS row base

  const int kq = (lane >> 4) << 3;
  const int rrow = lane & 15;

#define STAGE(kt, buf)                                                        \
  {                                                                           \
    char* bb = sm + (buf) * BUFB;                                             \
    const u16* pa = gA + (kt) * 64;                                           \
    const u16* pb = gB + (kt) * 64;                                           \
    gload16(pa,                  (u16*)(bb + (0 * 64 + wrow) * 128));         \
    gload16(pa + 64 * PK,        (u16*)(bb + (1 * 64 + wrow) * 128));         \
    gload16(pa + 128 * PK,       (u16*)(bb + (2 * 64 + wrow) * 128));         \
    gload16(pa + 192 * PK,       (u16*)(bb + (3 * 64 + wrow) * 128));         \
    gload16(pb,                  (u16*)(bb + ABY + (0 * 64 + wrow) * 128));   \
    gload16(pb + 64 * PK,        (u16*)(bb + ABY + (1 * 64 + wrow) * 128));   \
  }

  // prologue: tiles 0,1 in flight
  STAGE(0, 0);
  STAGE(1, 1);

  int cbuf = 0;   // compute buffer for tile k
  int sbuf = 2;   // stage buffer for tile k+2
  for (int k = 0; k < PNKT; ++k) {
    __builtin_amdgcn_sched_barrier(0);
    __builtin_amdgcn_s_barrier();  // all reads of sbuf (done at iter k-1) complete
    if (k < PNKT - 2) {
      STAGE(k + 2, sbuf);
      asm volatile("s_waitcnt vmcnt(12)" ::: "memory");  // tile k landed
    } else if (k == PNKT - 2) {
      asm volatile("s_waitcnt vmcnt(6)" ::: "memory");
    } else {
      asm volatile("s_waitcnt vmcnt(0)" ::: "memory");
    }
    __builtin_amdgcn_s_barrier();
    __builtin_amdgcn_sched_barrier(0);

    const char* bb = sm + cbuf * BUFB;
    s16x8 af[4][2], bfr[4][2];
#pragma unroll
    for (int i = 0; i < 4; ++i) {
      int ar = wr * 64 + i * 16 + rrow;
      const char* base = bb + ar * 128;
#pragma unroll
      for (int h = 0; h < 2; ++h) {
        int kk2 = (h * 32 + kq) * 2;
        af[i][h] = *(const s16x8*)(base + (kk2 ^ ((ar & 7) << 4)));
      }
    }
#pragma unroll
    for (int jf = 0; jf < 4; ++jf) {
      int br = wc * 64 + jf * 16 + rrow;
      const char* base = bb + ABY + br * 128;
#pragma unroll
      for (int h = 0; h < 2; ++h) {
        int kk2 = (h * 32 + kq) * 2;
        bfr[jf][h] = *(const s16x8*)(base + (kk2 ^ ((br & 7) << 4)));
      }
    }
#pragma unroll
    for (int i = 0; i < 4; ++i)
#pragma unroll
      for (int jf = 0; jf < 4; ++jf)
#pragma unroll
        for (int h = 0; h < 2; ++h)
          acc[i][jf] = __builtin_amdgcn_mfma_f32_16x16x32_bf16(
              af[i][h], bfr[jf][h], acc[i][jf], 0, 0, 0);

    // rotate buffers
    cbuf = (cbuf == 2) ? 0 : cbuf + 1;
    sbuf = (sbuf == 2) ? 0 : sbuf + 1;
  }
#undef STAGE

  const int crow0 = m0 + wr * 64 + ((lane >> 4) << 2);
  const int ccol0 = n0 + wc * 64 + rrow;
#pragma unroll
  for (int i = 0; i < 4; ++i)
#pragma unroll
    for (int jf = 0; jf < 4; ++jf)
#pragma unroll
      for (int r = 0; r < 4; ++r)
        C[(size_t)(crow0 + i * 16 + r) * ldc + (ccol0 + jf * 16)] = f2bf(acc[i][jf][r]);
}

// ---- epilogues (merged t+a cells, 4-wide) ----------------------------------
__global__ void ep1(const u16* __restrict__ G,
                    const float* __restrict__ bT, const float* __restrict__ bA,
                    u16* __restrict__ Aout,
                    float* __restrict__ CT, float* __restrict__ CA) {
  int idx = blockIdx.x * 256 + threadIdx.x;
  if (idx >= 8192 * 200) return;
  int t = idx / 200, r = idx % 200;
  int cell = r / 100, j0 = (r % 100) * 4;
  const u16* g = G + (size_t)t * GLD + cell * 2048;
  const float* b = cell ? bA : bT;
  float* Cout = cell ? CA : CT;
  f32x4 ip = ld4bf(g + j0);
  f32x4 op = ld4bf(g + 800 + j0);
  f32x4 up = ld4bf(g + 1200 + j0);
  u64 hv = 0;
  f32x4 cv;
#pragma unroll
  for (int k = 0; k < 4; ++k) {
    int j = j0 + k;
    float c = sigf(ip[k] + b[j]) * tanhf_(up[k] + b[1200 + j]);
    float h = sigf(op[k] + b[800 + j]) * tanhf_(c);
    cv[k] = c;
    hv |= (u64)f2bf(h) << (16 * k);
  }
  *(u64*)(Aout + (size_t)t * 832 + cell * 400 + j0) = hv;
  *(f32x4*)(Cout + (size_t)t * 400 + j0) = cv;
}

__global__ void ep2(const u16* __restrict__ G,
                    const float* __restrict__ bT, const float* __restrict__ bA,
                    const float* __restrict__ C1, const float* __restrict__ C2,
                    u16* __restrict__ Aout,
                    float* __restrict__ CT, float* __restrict__ CA) {
  int idx = blockIdx.x * 256 + threadIdx.x;
  if (idx >= 8192 * 200) return;
  int t = idx / 200, r = idx % 200;
  int cell = r / 100, j0 = (r % 100) * 4;
  const u16* g = G + (size_t)t * GLD + cell * 2048;
  const float* b = cell ? bA : bT;
  float* Cout = cell ? CA : CT;
  f32x4 ip  = ld4bf(g + j0);
  f32x4 f1p = ld4bf(g + 400 + j0);
  f32x4 f2p = ld4bf(g + 800 + j0);
  f32x4 op  = ld4bf(g + 1200 + j0);
  f32x4 up  = ld4bf(g + 1600 + j0);
  f32x4 c1 = *(const f32x4*)(C1 + (size_t)t * 400 + j0);
  f32x4 c2 = *(const f32x4*)(C2 + (size_t)t * 400 + j0);
  u64 hv = 0;
  f32x4 cv;
#pragma unroll
  for (int k = 0; k < 4; ++k) {
    int j = j0 + k;
    float c = sigf(ip[k] + b[j]) * tanhf_(up[k] + b[1200 + j])
            + sigf(f1p[k] + b[400 + j]) * c1[k]
            + sigf(f2p[k] + b[400 + j]) * c2[k];
    float h = sigf(op[k] + b[800 + j]) * tanhf_(c);
    cv[k] = c;
    hv |= (u64)f2bf(h) << (16 * k);
  }
  *(u64*)(Aout + (size_t)t * 832 + cell * 400 + j0) = hv;
  if (Cout) *(f32x4*)(Cout + (size_t)t * 400 + j0) = cv;
}

__global__ void ep_out(const u16* __restrict__ G,
                       const float* __restrict__ bcur, const float* __restrict__ bac,
                       const float* __restrict__ bap, float* __restrict__ out) {
  int idx = blockIdx.x * 256 + threadIdx.x;
  if (idx >= 8192 * 162) return;
  int t = idx / 162, j = idx % 162;
  float v = bf2f(G[(size_t)t * GLD + j]);
  if (j < 55)       out[t * 55 + j] = v + bcur[j];
  else if (j < 107) out[450560 + t * 52 + (j - 55)] = v + bac[j - 55];
  else              out[876544 + t * 55 + (j - 107)] = v + bap[j - 107];
}

// ---- launch ----------------------------------------------------------------
extern "C" void kernel_launch(void* const* d_in, const int* in_sizes, int n_in,
                              void* d_out, int out_size, void* d_ws, size_t ws_size,
                              hipStream_t stream) {
  const float* x_temp = (const float*)d_in[0];
  const float* x_air  = (const float*)d_in[1];
  const float* Wx_t1  = (const float*)d_in[2];
  const float* b_t1   = (const float*)d_in[4];
  const float* Wx_t2  = (const float*)d_in[5];
  const float* U_t2   = (const float*)d_in[6];
  const float* b_t2   = (const float*)d_in[7];
  const float* Wx_t3  = (const float*)d_in[8];
  const float* U_t3   = (const float*)d_in[9];
  const float* b_t3   = (const float*)d_in[10];
  const float* Wx_a1  = (const float*)d_in[11];
  const float* b_a1   = (const float*)d_in[13];
  const float* Wx_a2  = (const float*)d_in[14];
  const float* U_a2   = (const float*)d_in[15];
  const float* b_a2   = (const float*)d_in[16];
  const float* Wx_a3  = (const float*)d_in[17];
  const float* U_a3   = (const float*)d_in[18];
  const float* b_a3   = (const float*)d_in[19];
  const float* W_cur  = (const float*)d_in[20];
  const float* b_cur  = (const float*)d_in[21];
  const float* W_ac   = (const float*)d_in[22];
  const float* b_ac   = (const float*)d_in[23];
  const float* W_ap   = (const float*)d_in[24];
  const float* b_ap   = (const float*)d_in[25];

  char* ws = (char*)d_ws;
  u16*   A0t = (u16*)(ws + 0);          // [8192][64]
  u16*   A0a = (u16*)(ws + 1048576);
  u16*   B1t = (u16*)(ws + 2097152);    // [1664][64]
  u16*   B1a = (u16*)(ws + 2310144);
  u16*   Bp  = (u16*)(ws + 2523136);    // [256][832]
  u16*   A1  = (u16*)(ws + 2949120);    // [8192][832]  (ht|ha|pad)
  u16*   A2  = (u16*)(ws + 16580608);
  u16*   A3  = (u16*)(ws + 30212096);
  float* Ct  = (float*)(ws + 43843584); // [8192][400]
  float* Ca  = (float*)(ws + 56950784);
  float* C2t = (float*)(ws + 70057984);
  float* C2a = (float*)(ws + 83165184);
  u16*   B2  = (u16*)(ws + 96272384);   // [4096][832] (t rows 0..2047, a rows 2048..)
  u16*   B3  = (u16*)(ws + 103088128);
  u16*   G   = (u16*)(ws + 109903872);  // [8192][4096] bf16
  float* out = (float*)d_out;

  dim3 blk(256);
  zero_pads<<<768, blk, 0, stream>>>(A1, A2, A3);
  pad_cast<<<2048, blk, 0, stream>>>(x_temp, A0t, 55, 64, 8192);
  pad_cast<<<2048, blk, 0, stream>>>(x_air,  A0a, 55, 64, 8192);
  transpose_cast<<<416, blk, 0, stream>>>(Wx_t1, B1t, 55, 1600);
  transpose_cast<<<416, blk, 0, stream>>>(Wx_a1, B1a, 55, 1600);
  build_cell_B<<<dim3(64, 13), blk, 0, stream>>>(Wx_t2, U_t2, Wx_a2, U_a2, B2);
  build_cell_B<<<dim3(64, 13), blk, 0, stream>>>(Wx_t3, U_t3, Wx_a3, U_a3, B3);
  build_proj_B<<<832, blk, 0, stream>>>(W_cur, W_ac, W_ap, Bp);

  // layer 1 (two GEMMs, one merged epilogue)
  gemm_lds<<<dim3(13, 64), blk, 0, stream>>>(A0t, B1t, G, 64, GLD);
  gemm_lds<<<dim3(13, 64), blk, 0, stream>>>(A0a, B1a, G + 2048, 64, GLD);
  ep1<<<6400, blk, 0, stream>>>(G, b_t1, b_a1, A1, Ct, Ca);
  // layer 2 (one merged GEMM, pipelined)
  gemm_pipe<<<dim3(32, 32), dim3(512), 0, stream>>>(A1, B2, G, GLD);
  ep2<<<6400, blk, 0, stream>>>(G, b_t2, b_a2, Ct, Ca, A2, C2t, C2a);
  // layer 3 (c outputs dead -> skip)
  gemm_pipe<<<dim3(32, 32), dim3(512), 0, stream>>>(A2, B3, G, GLD);
  ep2<<<6400, blk, 0, stream>>>(G, b_t3, b_a3, C2t, C2a, A3, nullptr, nullptr);
  // projections
  gemm_lds<<<dim3(2, 64), blk, 0, stream>>>(A3, Bp, G, 832, GLD);
  ep_out<<<5184, blk, 0, stream>>>(G, b_cur, b_ac, b_ap, out);
}

// Round 9
// 383.495 us; speedup vs baseline: 1.2459x; 1.0619x over previous
//
#include <hip/hip_runtime.h>
#include <hip/hip_bf16.h>

typedef unsigned short u16;
typedef unsigned int u32;
typedef unsigned long long u64;
typedef __attribute__((ext_vector_type(4))) float f32x4;
typedef __attribute__((ext_vector_type(8))) short s16x8;
typedef __attribute__((ext_vector_type(4))) int i32x4;

__device__ inline u16 f2bf(float f) {
  union { float f; u32 u; } v; v.f = f;
  u32 r = (v.u + 0x7FFFu + ((v.u >> 16) & 1u)) >> 16;
  return (u16)r;
}
__device__ inline float bf2f(u16 h) { return __uint_as_float((u32)h << 16); }
__device__ inline float sigf(float x) { return 1.0f / (1.0f + __expf(-x)); }
__device__ inline float tanhf_(float x) {
  float ax = fabsf(x);
  float e = __expf(-2.0f * ax);
  float r = (1.0f - e) / (1.0f + e);
  return copysignf(r, x);
}
__device__ inline f32x4 ld4bf(const u16* p) {
  u64 v = *(const u64*)p;
  f32x4 r;
  r.x = __uint_as_float((u32)(v & 0xFFFFu) << 16);
  r.y = __uint_as_float((u32)((v >> 16) & 0xFFFFu) << 16);
  r.z = __uint_as_float((u32)((v >> 32) & 0xFFFFu) << 16);
  r.w = __uint_as_float((u32)((v >> 48) & 0xFFFFu) << 16);
  return r;
}
__device__ inline void gload16(const u16* g, u16* l) {
  __builtin_amdgcn_global_load_lds(
      (const __attribute__((address_space(1))) void*)(g),
      (__attribute__((address_space(3))) void*)(l), 16, 0, 0);
}

#define GLD 4096  // G row stride (u16 / bf16)

// ---- prep kernels ----------------------------------------------------------
__global__ void zero_pads(u16* __restrict__ A1, u16* __restrict__ A2,
                          u16* __restrict__ A3) {
  int idx = blockIdx.x * 256 + threadIdx.x;  // 3 * 8192 * 8 quads
  if (idx >= 196608) return;
  int b = idx / 65536, r = idx % 65536;
  int t = r / 8, q = r % 8;
  u16* A = (b == 0) ? A1 : (b == 1) ? A2 : A3;
  *(u64*)(A + (size_t)t * 832 + 800 + q * 4) = 0ULL;
}

__global__ void pad_cast(const float* __restrict__ src, u16* __restrict__ dst,
                         int srcCols, int dstCols, int rows) {
  int idx = blockIdx.x * 256 + threadIdx.x;
  if (idx >= rows * dstCols) return;
  int r = idx / dstCols, c = idx % dstCols;
  float v = (c < srcCols) ? src[r * srcCols + c] : 0.f;
  dst[idx] = f2bf(v);
}

__global__ void transpose_cast(const float* __restrict__ src, u16* __restrict__ dst,
                               int srcK, int srcN) {
  int idx = blockIdx.x * 256 + threadIdx.x;
  if (idx >= 64 * 1664) return;
  int k = idx / 1664, n = idx % 1664;
  float v = (k < srcK && n < srcN) ? src[k * srcN + n] : 0.f;
  dst[n * 64 + k] = f2bf(v);
}

// Combined layer-2/3 weights, K-major: dst [4096][832] bf16, LDS-tiled (both
// sides coalesced). np: cell=np>>11; n=np&2047 in [0,2000): g=n/400 {i,f1,f2,o,u},
// j=n%400. col r: r<400 ht coeff else ha.
__global__ __launch_bounds__(256) void build_cell_B(
    const float* __restrict__ WxT, const float* __restrict__ UT,
    const float* __restrict__ WxA, const float* __restrict__ UA,
    u16* __restrict__ dst) {
  __shared__ float tile[64][65];
  const int np0 = blockIdx.x * 64;
  const int r0 = blockIdx.y * 64;
  const int tx = threadIdx.x & 63, ty = threadIdx.x >> 6;

  const int np = np0 + tx;
  const int cell = np >> 11;
  const int n = np & 2047;
  const float* Wx = cell ? WxA : WxT;
  const float* U  = cell ? UA  : UT;
  int g = 0, j = 0, gc = 0;
  if (n < 2000) {
    g = n / 400; j = n % 400;
    gc = (g == 0) ? j : (g <= 2) ? 400 + j : (g == 3) ? 800 + j : 1200 + j;
  }
#pragma unroll
  for (int it = 0; it < 16; ++it) {
    int r = r0 + it * 4 + ty;
    float v = 0.f;
    if (n < 2000 && r < 800) {
      bool htside = (r < 400);
      int rr = htside ? r : r - 400;
      float wx = Wx[rr * 1600 + gc];
      float uu = U [rr * 1600 + gc];
      if (cell == 0) { // x = ht = h1
        if (htside) v = (g == 2) ? wx : wx + uu;   // f2 col: Wxf only
        else        v = (g == 1) ? 0.f : uu;        // f1 col: no ha term
      } else {          // x = ha = h2
        if (htside) v = (g == 2) ? 0.f : uu;
        else        v = (g == 1) ? wx : wx + uu;
      }
    }
    tile[tx][it * 4 + ty] = v;
  }
  __syncthreads();
#pragma unroll
  for (int it = 0; it < 16; ++it) {
    int npw = np0 + it * 4 + ty;
    dst[(size_t)npw * 832 + r0 + tx] = f2bf(tile[it * 4 + ty][tx]);
  }
}

__global__ void build_proj_B(const float* __restrict__ Wcur, const float* __restrict__ Wac,
                             const float* __restrict__ Wap, u16* __restrict__ dst) {
  int idx = blockIdx.x * 256 + threadIdx.x;
  if (idx >= 256 * 832) return;
  int n = idx / 832, r = idx % 832;
  float v = 0.f;
  if (r < 800) {
    if (n < 55) v = Wcur[r * 55 + n];
    else if (n < 107) { if (r < 400) v = Wac[r * 52 + (n - 55)]; }
    else if (n < 162) { if (r >= 400) v = Wap[(r - 400) * 55 + (n - 107)]; }
  }
  dst[idx] = f2bf(v);
}

// ---- GEMM (small shapes): 128x128 tile, 2-phase, round-2/3-verified --------
__global__ __launch_bounds__(256) void gemm_lds(
    const u16* __restrict__ A, const u16* __restrict__ Bt,
    u16* __restrict__ C, int K, int ldc) {
  __shared__ u16 As[128 * 64];
  __shared__ u16 Bs[128 * 64];
  const int tid = threadIdx.x;
  const int lane = tid & 63;
  const int wid = tid >> 6;

  const int nwg = gridDim.x * gridDim.y;
  const int bid = blockIdx.y * gridDim.x + blockIdx.x;
  const int swz = (bid & 7) * (nwg >> 3) + (bid >> 3);
  const int m0 = (swz / gridDim.x) * 128;
  const int n0 = (swz % gridDim.x) * 128;

  const int wm = (wid >> 1) << 6;
  const int wn = (wid & 1) << 6;

  f32x4 acc[4][4];
#pragma unroll
  for (int i = 0; i < 4; ++i)
#pragma unroll
    for (int j = 0; j < 4; ++j) acc[i][j] = (f32x4){0.f, 0.f, 0.f, 0.f};

  const int nkt = K >> 6;
  const int l8 = lane >> 3, lb = lane & 7;
  const int scol = (lb ^ l8) << 3;
  const u16* gA = A + (size_t)(m0 + wid * 8 + l8) * K + scol;
  const u16* gB = Bt + (size_t)(n0 + wid * 8 + l8) * K + scol;
  u16* lA = As + wid * 8 * 64;
  u16* lB = Bs + wid * 8 * 64;

  const int kq = (lane >> 4) << 3;
  const int rrow = lane & 15;

  for (int kt = 0; kt < nkt; ++kt) {
    __syncthreads();
    const u16* pa = gA + kt * 64;
    const u16* pb = gB + kt * 64;
#pragma unroll
    for (int c = 0; c < 4; ++c) {
      gload16(pa + (size_t)(c * 32) * K, lA + c * 2048);
      gload16(pb + (size_t)(c * 32) * K, lB + c * 2048);
    }
    __syncthreads();
#pragma unroll
    for (int half = 0; half < 2; ++half) {
      const int kk = half * 32 + kq;
      s16x8 af[4], bfr[4];
#pragma unroll
      for (int f = 0; f < 4; ++f) {
        int ar = wm + f * 16 + rrow;
        af[f] = *(const s16x8*)((const char*)As + ar * 128 + ((kk * 2) ^ ((ar & 7) << 4)));
        int br = wn + f * 16 + rrow;
        bfr[f] = *(const s16x8*)((const char*)Bs + br * 128 + ((kk * 2) ^ ((br & 7) << 4)));
      }
#pragma unroll
      for (int i = 0; i < 4; ++i)
#pragma unroll
        for (int j = 0; j < 4; ++j)
          acc[i][j] = __builtin_amdgcn_mfma_f32_16x16x32_bf16(af[i], bfr[j], acc[i][j], 0, 0, 0);
    }
  }

  const int crow0 = m0 + wm + ((lane >> 4) << 2);
  const int ccol0 = n0 + wn + rrow;
#pragma unroll
  for (int i = 0; i < 4; ++i)
#pragma unroll
    for (int j = 0; j < 4; ++j)
#pragma unroll
      for (int r = 0; r < 4; ++r)
        C[(size_t)(crow0 + i * 16 + r) * ldc + (ccol0 + j * 16)] = f2bf(acc[i][j][r]);
}

// ---- GEMM (big shapes): 256x128 tile, fine 4-phase/K-tile, counted vmcnt ---
// K=832 (13 K-tiles). 512 thr, 8 waves (4M x 2N), per-wave 64x64 out.
// 3 buffers x (A 32KB + B 16KB); K-tile t lives in buffer t%3; its 6 chunks
// are staged during group t-2 (2/2/1/1 over the 4 phases). Proof of safety:
// at group g phase 3, vmcnt(6) leaves only the 6 chunks issued during g
// outstanding => all chunks of K-tile g+1 (issued during g-1) have landed;
// the phase barrier then publishes them to all waves. Never vmcnt(0) until
// the tail. Per phase: {ds_read frags | stage chunk(s)} BAR {setprio1, 8
// MFMA, setprio0} BAR, sched_barrier(0) at every barrier (rule 18).
#define PK 832
#define NKT 13
#define ABY 32768   // A tile bytes: 256*64*2
#define BUFB 49152  // A + B(128*64*2)

__global__ __launch_bounds__(512, 2) void gemm_256(
    const u16* __restrict__ A, const u16* __restrict__ Bt,
    u16* __restrict__ C, int ldc) {
  __shared__ char sm[3 * BUFB];  // 144 KiB
  const int tid = threadIdx.x;
  const int lane = tid & 63;
  const int wid = tid >> 6;

  const int nwg = gridDim.x * gridDim.y;
  const int bid = blockIdx.y * gridDim.x + blockIdx.x;
  const int swz = (bid & 7) * (nwg >> 3) + (bid >> 3);
  const int m0 = (swz / gridDim.x) * 256;
  const int n0 = (swz % gridDim.x) * 128;

  const int wr = wid >> 1;   // 0..3 (M, 64-row block)
  const int wc = wid & 1;    // 0..1 (N, 64-col block)

  f32x4 acc[4][4];
#pragma unroll
  for (int i = 0; i < 4; ++i)
#pragma unroll
    for (int j = 0; j < 4; ++j) acc[i][j] = (f32x4){0.f, 0.f, 0.f, 0.f};

  // staging: linear LDS dest + pre-swizzled global source (rule 21)
  const int q = lane >> 3, lb = lane & 7;
  const int scol = (lb ^ q) << 3;
  const u16* gA = A + (size_t)(m0 + wid * 8 + q) * PK + scol;
  const u16* gB = Bt + (size_t)(n0 + wid * 8 + q) * PK + scol;
  const int wrow = wid * 8;

#define CHA(kt, buf, c) gload16(gA + (kt) * 64 + (size_t)((c) * 64) * PK,      \
                                (u16*)(sm + (buf) * BUFB + ((c) * 64 + wrow) * 128))
#define CHB(kt, buf, c) gload16(gB + (kt) * 64 + (size_t)((c) * 64) * PK,      \
                                (u16*)(sm + (buf) * BUFB + ABY + ((c) * 64 + wrow) * 128))

  const int kq = (lane >> 4) << 3;
  const int rrow = lane & 15;

  // prologue: stage K-tiles 0,1 (6 chunks each, fixed order A0..A3,B0,B1)
  CHA(0, 0, 0); CHA(0, 0, 1); CHA(0, 0, 2); CHA(0, 0, 3);
  CHB(0, 0, 0); CHB(0, 0, 1);
  CHA(1, 1, 0); CHA(1, 1, 1); CHA(1, 1, 2); CHA(1, 1, 3);
  CHB(1, 1, 0); CHB(1, 1, 1);
  asm volatile("s_waitcnt vmcnt(6)" ::: "memory");  // K-tile 0 landed
  __builtin_amdgcn_sched_barrier(0);
  __builtin_amdgcn_s_barrier();
  __builtin_amdgcn_sched_barrier(0);

  int cur = 0;
  for (int t = 0; t < NKT; ++t) {
    const char* bb = sm + cur * BUFB;
    const int sb = (cur == 0) ? 2 : cur - 1;  // (t+2)%3
    const bool st = (t + 2) < NKT;
    s16x8 bfr[4][2];

    // ---- phase 0: B frags (8 reads) + A row 0 (2); stage A chunks 0,1 ----
    {
#pragma unroll
      for (int jf = 0; jf < 4; ++jf) {
        int br = wc * 64 + jf * 16 + rrow;
        const char* base = bb + ABY + br * 128;
#pragma unroll
        for (int h = 0; h < 2; ++h)
          bfr[jf][h] = *(const s16x8*)(base + (((h * 32 + kq) * 2) ^ ((br & 7) << 4)));
      }
      int ar = wr * 64 + rrow;
      const char* abase = bb + ar * 128;
      s16x8 af0 = *(const s16x8*)(abase + ((kq * 2) ^ ((ar & 7) << 4)));
      s16x8 af1 = *(const s16x8*)(abase + (((32 + kq) * 2) ^ ((ar & 7) << 4)));
      if (st) { CHA(t + 2, sb, 0); CHA(t + 2, sb, 1); }
      __builtin_amdgcn_sched_barrier(0);
      __builtin_amdgcn_s_barrier();
      __builtin_amdgcn_sched_barrier(0);
      __builtin_amdgcn_s_setprio(1);
#pragma unroll
      for (int jf = 0; jf < 4; ++jf) {
        acc[0][jf] = __builtin_amdgcn_mfma_f32_16x16x32_bf16(af0, bfr[jf][0], acc[0][jf], 0, 0, 0);
        acc[0][jf] = __builtin_amdgcn_mfma_f32_16x16x32_bf16(af1, bfr[jf][1], acc[0][jf], 0, 0, 0);
      }
      __builtin_amdgcn_s_setprio(0);
      __builtin_amdgcn_sched_barrier(0);
      __builtin_amdgcn_s_barrier();
      __builtin_amdgcn_sched_barrier(0);
    }
    // ---- phases 1,2: A row i; stage {A2,A3} / {B0} ----
#pragma unroll
    for (int i = 1; i < 3; ++i) {
      int ar = wr * 64 + i * 16 + rrow;
      const char* abase = bb + ar * 128;
      s16x8 af0 = *(const s16x8*)(abase + ((kq * 2) ^ ((ar & 7) << 4)));
      s16x8 af1 = *(const s16x8*)(abase + (((32 + kq) * 2) ^ ((ar & 7) << 4)));
      if (st) {
        if (i == 1) { CHA(t + 2, sb, 2); CHA(t + 2, sb, 3); }
        else        { CHB(t + 2, sb, 0); }
      }
      __builtin_amdgcn_sched_barrier(0);
      __builtin_amdgcn_s_barrier();
      __builtin_amdgcn_sched_barrier(0);
      __builtin_amdgcn_s_setprio(1);
#pragma unroll
      for (int jf = 0; jf < 4; ++jf) {
        acc[i][jf] = __builtin_amdgcn_mfma_f32_16x16x32_bf16(af0, bfr[jf][0], acc[i][jf], 0, 0, 0);
        acc[i][jf] = __builtin_amdgcn_mfma_f32_16x16x32_bf16(af1, bfr[jf][1], acc[i][jf], 0, 0, 0);
      }
      __builtin_amdgcn_s_setprio(0);
      __builtin_amdgcn_sched_barrier(0);
      __builtin_amdgcn_s_barrier();
      __builtin_amdgcn_sched_barrier(0);
    }
    // ---- phase 3: A row 3; stage B1; vmcnt gate for K-tile t+1 ----
    {
      int ar = wr * 64 + 48 + rrow;
      const char* abase = bb + ar * 128;
      s16x8 af0 = *(const s16x8*)(abase + ((kq * 2) ^ ((ar & 7) << 4)));
      s16x8 af1 = *(const s16x8*)(abase + (((32 + kq) * 2) ^ ((ar & 7) << 4)));
      if (st) {
        CHB(t + 2, sb, 1);
        asm volatile("s_waitcnt vmcnt(6)" ::: "memory");  // all of K-tile t+1 landed
      } else {
        asm volatile("s_waitcnt vmcnt(0)" ::: "memory");  // tail drain
      }
      __builtin_amdgcn_sched_barrier(0);
      __builtin_amdgcn_s_barrier();
      __builtin_amdgcn_sched_barrier(0);
      __builtin_amdgcn_s_setprio(1);
#pragma unroll
      for (int jf = 0; jf < 4; ++jf) {
        acc[3][jf] = __builtin_amdgcn_mfma_f32_16x16x32_bf16(af0, bfr[jf][0], acc[3][jf], 0, 0, 0);
        acc[3][jf] = __builtin_amdgcn_mfma_f32_16x16x32_bf16(af1, bfr[jf][1], acc[3][jf], 0, 0, 0);
      }
      __builtin_amdgcn_s_setprio(0);
      __builtin_amdgcn_sched_barrier(0);
      __builtin_amdgcn_s_barrier();
      __builtin_amdgcn_sched_barrier(0);
    }
    cur = (cur == 2) ? 0 : cur + 1;
  }
#undef CHA
#undef CHB

  // ---- coalesced C-write: stage per-wave 64x64 bf16 tile in LDS, then
  // write 128B-contiguous rows (full sectors, no RMW fetch). LDS is free
  // (all DMA drained by tail vmcnt(0); all reads done before final barrier).
  u16* eps = (u16*)(sm + wid * 8192);
#pragma unroll
  for (int i = 0; i < 4; ++i)
#pragma unroll
    for (int jf = 0; jf < 4; ++jf)
#pragma unroll
      for (int r = 0; r < 4; ++r) {
        int row = i * 16 + ((lane >> 4) << 2) + r;
        int colb = (jf * 16 + rrow) * 2;
        *(u16*)((char*)eps + row * 128 + (colb ^ ((row & 7) << 4))) = f2bf(acc[i][jf][r]);
      }
  const size_t crowW = m0 + wr * 64;
  const int ccolW = n0 + wc * 64;
#pragma unroll
  for (int p = 0; p < 8; ++p) {
    int row = p * 8 + (lane >> 3);
    int segb = (lane & 7) * 16;
    i32x4 v = *(const i32x4*)((char*)eps + row * 128 + (segb ^ ((row & 7) << 4)));
    *(i32x4*)(C + (crowW + row) * (size_t)ldc + ccolW + (lane & 7) * 8) = v;
  }
}

// ---- epilogues -------------------------------------------------------------
// layer1: gates i,-,o,u at cols 0/800/1200 (+cell*2048); children zero -> c=i*u
__global__ void ep1(const u16* __restrict__ G,
                    const float* __restrict__ bT, const float* __restrict__ bA,
                    u16* __restrict__ Aout,
                    float* __restrict__ CT, float* __restrict__ CA) {
  int idx = blockIdx.x * 256 + threadIdx.x;
  if (idx >= 8192 * 200) return;
  int t = idx / 200, r = idx % 200;
  int cell = r / 100, j0 = (r % 100) * 4;
  const u16* g = G + (size_t)t * GLD + cell * 2048;
  const float* b = cell ? bA : bT;
  float* Cout = cell ? CA : CT;
  f32x4 ip = ld4bf(g + j0);
  f32x4 op = ld4bf(g + 800 + j0);
  f32x4 up = ld4bf(g + 1200 + j0);
  u64 hv = 0;
  f32x4 cv;
#pragma unroll
  for (int k = 0; k < 4; ++k) {
    int j = j0 + k;
    float c = sigf(ip[k] + b[j]) * tanhf_(up[k] + b[1200 + j]);
    float h = sigf(op[k] + b[800 + j]) * tanhf_(c);
    cv[k] = c;
    hv |= (u64)f2bf(h) << (16 * k);
  }
  *(u64*)(Aout + (size_t)t * 832 + cell * 400 + j0) = hv;
  *(f32x4*)(Cout + (size_t)t * 400 + j0) = cv;
}

// layer2/3: one thread does BOTH cells for (t, j-quad) -> c1/c2 read once.
__global__ void ep2(const u16* __restrict__ G,
                    const float* __restrict__ bT, const float* __restrict__ bA,
                    const float* __restrict__ C1, const float* __restrict__ C2,
                    u16* __restrict__ Aout,
                    float* __restrict__ CT, float* __restrict__ CA) {
  int idx = blockIdx.x * 256 + threadIdx.x;
  if (idx >= 8192 * 100) return;
  int t = idx / 100, j0 = (idx % 100) * 4;
  f32x4 c1 = *(const f32x4*)(C1 + (size_t)t * 400 + j0);
  f32x4 c2 = *(const f32x4*)(C2 + (size_t)t * 400 + j0);
#pragma unroll
  for (int cell = 0; cell < 2; ++cell) {
    const u16* g = G + (size_t)t * GLD + cell * 2048;
    const float* b = cell ? bA : bT;
    f32x4 ip  = ld4bf(g + j0);
    f32x4 f1p = ld4bf(g + 400 + j0);
    f32x4 f2p = ld4bf(g + 800 + j0);
    f32x4 op  = ld4bf(g + 1200 + j0);
    f32x4 up  = ld4bf(g + 1600 + j0);
    u64 hv = 0;
    f32x4 cv;
#pragma unroll
    for (int k = 0; k < 4; ++k) {
      int j = j0 + k;
      float c = sigf(ip[k] + b[j]) * tanhf_(up[k] + b[1200 + j])
              + sigf(f1p[k] + b[400 + j]) * c1[k]
              + sigf(f2p[k] + b[400 + j]) * c2[k];
      float h = sigf(op[k] + b[800 + j]) * tanhf_(c);
      cv[k] = c;
      hv |= (u64)f2bf(h) << (16 * k);
    }
    *(u64*)(Aout + (size_t)t * 832 + cell * 400 + j0) = hv;
    if (CT) {
      float* Cout = cell ? CA : CT;
      *(f32x4*)(Cout + (size_t)t * 400 + j0) = cv;
    }
  }
}

__global__ void ep_out(const u16* __restrict__ G,
                       const float* __restrict__ bcur, const float* __restrict__ bac,
                       const float* __restrict__ bap, float* __restrict__ out) {
  int idx = blockIdx.x * 256 + threadIdx.x;
  if (idx >= 8192 * 162) return;
  int t = idx / 162, j = idx % 162;
  float v = bf2f(G[(size_t)t * GLD + j]);
  if (j < 55)       out[t * 55 + j] = v + bcur[j];
  else if (j < 107) out[450560 + t * 52 + (j - 55)] = v + bac[j - 55];
  else              out[876544 + t * 55 + (j - 107)] = v + bap[j - 107];
}

// ---- launch ----------------------------------------------------------------
extern "C" void kernel_launch(void* const* d_in, const int* in_sizes, int n_in,
                              void* d_out, int out_size, void* d_ws, size_t ws_size,
                              hipStream_t stream) {
  const float* x_temp = (const float*)d_in[0];
  const float* x_air  = (const float*)d_in[1];
  const float* Wx_t1  = (const float*)d_in[2];
  const float* b_t1   = (const float*)d_in[4];
  const float* Wx_t2  = (const float*)d_in[5];
  const float* U_t2   = (const float*)d_in[6];
  const float* b_t2   = (const float*)d_in[7];
  const float* Wx_t3  = (const float*)d_in[8];
  const float* U_t3   = (const float*)d_in[9];
  const float* b_t3   = (const float*)d_in[10];
  const float* Wx_a1  = (const float*)d_in[11];
  const float* b_a1   = (const float*)d_in[13];
  const float* Wx_a2  = (const float*)d_in[14];
  const float* U_a2   = (const float*)d_in[15];
  const float* b_a2   = (const float*)d_in[16];
  const float* Wx_a3  = (const float*)d_in[17];
  const float* U_a3   = (const float*)d_in[18];
  const float* b_a3   = (const float*)d_in[19];
  const float* W_cur  = (const float*)d_in[20];
  const float* b_cur  = (const float*)d_in[21];
  const float* W_ac   = (const float*)d_in[22];
  const float* b_ac   = (const float*)d_in[23];
  const float* W_ap   = (const float*)d_in[24];
  const float* b_ap   = (const float*)d_in[25];

  char* ws = (char*)d_ws;
  u16*   A0t = (u16*)(ws + 0);          // [8192][64]
  u16*   A0a = (u16*)(ws + 1048576);
  u16*   B1t = (u16*)(ws + 2097152);    // [1664][64]
  u16*   B1a = (u16*)(ws + 2310144);
  u16*   Bp  = (u16*)(ws + 2523136);    // [256][832]
  u16*   A1  = (u16*)(ws + 2949120);    // [8192][832]  (ht|ha|pad)
  u16*   A2  = (u16*)(ws + 16580608);
  u16*   A3  = (u16*)(ws + 30212096);
  float* Ct  = (float*)(ws + 43843584); // [8192][400]
  float* Ca  = (float*)(ws + 56950784);
  float* C2t = (float*)(ws + 70057984);
  float* C2a = (float*)(ws + 83165184);
  u16*   B2  = (u16*)(ws + 96272384);   // [4096][832] (t rows 0..2047, a rows 2048..)
  u16*   B3  = (u16*)(ws + 103088128);
  u16*   G   = (u16*)(ws + 109903872);  // [8192][4096] bf16
  float* out = (float*)d_out;

  dim3 blk(256);
  zero_pads<<<768, blk, 0, stream>>>(A1, A2, A3);
  pad_cast<<<2048, blk, 0, stream>>>(x_temp, A0t, 55, 64, 8192);
  pad_cast<<<2048, blk, 0, stream>>>(x_air,  A0a, 55, 64, 8192);
  transpose_cast<<<416, blk, 0, stream>>>(Wx_t1, B1t, 55, 1600);
  transpose_cast<<<416, blk, 0, stream>>>(Wx_a1, B1a, 55, 1600);
  build_cell_B<<<dim3(64, 13), blk, 0, stream>>>(Wx_t2, U_t2, Wx_a2, U_a2, B2);
  build_cell_B<<<dim3(64, 13), blk, 0, stream>>>(Wx_t3, U_t3, Wx_a3, U_a3, B3);
  build_proj_B<<<832, blk, 0, stream>>>(W_cur, W_ac, W_ap, Bp);

  // layer 1 (two GEMMs, one merged epilogue)
  gemm_lds<<<dim3(13, 64), blk, 0, stream>>>(A0t, B1t, G, 64, GLD);
  gemm_lds<<<dim3(13, 64), blk, 0, stream>>>(A0a, B1a, G + 2048, 64, GLD);
  ep1<<<6400, blk, 0, stream>>>(G, b_t1, b_a1, A1, Ct, Ca);
  // layer 2 (one merged GEMM, fine-pipelined)
  gemm_256<<<dim3(32, 32), dim3(512), 0, stream>>>(A1, B2, G, GLD);
  ep2<<<3200, blk, 0, stream>>>(G, b_t2, b_a2, Ct, Ca, A2, C2t, C2a);
  // layer 3 (c outputs dead -> skip)
  gemm_256<<<dim3(32, 32), dim3(512), 0, stream>>>(A2, B3, G, GLD);
  ep2<<<3200, blk, 0, stream>>>(G, b_t3, b_a3, C2t, C2a, A3, nullptr, nullptr);
  // projections
  gemm_lds<<<dim3(2, 64), blk, 0, stream>>>(A3, Bp, G, 832, GLD);
  ep_out<<<5184, blk, 0, stream>>>(G, b_cur, b_ac, b_ap, out);
}

// Round 12
// 373.761 us; speedup vs baseline: 1.2783x; 1.0260x over previous
//
#include <hip/hip_runtime.h>
#include <hip/hip_bf16.h>

typedef unsigned short u16;
typedef unsigned int u32;
typedef unsigned long long u64;
typedef __attribute__((ext_vector_type(4))) float f32x4;
typedef __attribute__((ext_vector_type(8))) short s16x8;
typedef __attribute__((ext_vector_type(4))) int i32x4;

__device__ inline u16 f2bf(float f) {
  union { float f; u32 u; } v; v.f = f;
  u32 r = (v.u + 0x7FFFu + ((v.u >> 16) & 1u)) >> 16;
  return (u16)r;
}
__device__ inline float bf2f(u16 h) { return __uint_as_float((u32)h << 16); }
__device__ inline float sigf(float x) { return 1.0f / (1.0f + __expf(-x)); }
__device__ inline float tanhf_(float x) {
  float ax = fabsf(x);
  float e = __expf(-2.0f * ax);
  float r = (1.0f - e) / (1.0f + e);
  return copysignf(r, x);
}
__device__ inline f32x4 ld4bf(const u16* p) {
  u64 v = *(const u64*)p;
  f32x4 r;
  r.x = __uint_as_float((u32)(v & 0xFFFFu) << 16);
  r.y = __uint_as_float((u32)((v >> 16) & 0xFFFFu) << 16);
  r.z = __uint_as_float((u32)((v >> 32) & 0xFFFFu) << 16);
  r.w = __uint_as_float((u32)((v >> 48) & 0xFFFFu) << 16);
  return r;
}
__device__ inline void gload16(const u16* g, u16* l) {
  __builtin_amdgcn_global_load_lds(
      (const __attribute__((address_space(1))) void*)(g),
      (__attribute__((address_space(3))) void*)(l), 16, 0, 0);
}

#define GLD 4096  // G row stride (u16 / bf16)

// ---- prep kernels ----------------------------------------------------------
__global__ void zero_pads(u16* __restrict__ A1, u16* __restrict__ A2,
                          u16* __restrict__ A3) {
  int idx = blockIdx.x * 256 + threadIdx.x;  // 3 * 8192 * 8 quads
  if (idx >= 196608) return;
  int b = idx / 65536, r = idx % 65536;
  int t = r / 8, q = r % 8;
  u16* A = (b == 0) ? A1 : (b == 1) ? A2 : A3;
  *(u64*)(A + (size_t)t * 832 + 800 + q * 4) = 0ULL;
}

__global__ void pad_cast(const float* __restrict__ src, u16* __restrict__ dst,
                         int srcCols, int dstCols, int rows) {
  int idx = blockIdx.x * 256 + threadIdx.x;
  if (idx >= rows * dstCols) return;
  int r = idx / dstCols, c = idx % dstCols;
  float v = (c < srcCols) ? src[r * srcCols + c] : 0.f;
  dst[idx] = f2bf(v);
}

__global__ void transpose_cast(const float* __restrict__ src, u16* __restrict__ dst,
                               int srcK, int srcN) {
  int idx = blockIdx.x * 256 + threadIdx.x;
  if (idx >= 64 * 1664) return;
  int k = idx / 1664, n = idx % 1664;
  float v = (k < srcK && n < srcN) ? src[k * srcN + n] : 0.f;
  dst[n * 64 + k] = f2bf(v);
}

// Combined layer-2/3 weights, K-major: dst [4096][832] bf16, LDS-tiled (both
// sides coalesced). np: cell=np>>11; n=np&2047 in [0,2000): g=n/400 {i,f1,f2,o,u},
// j=n%400. col r: r<400 ht coeff else ha.
__global__ __launch_bounds__(256) void build_cell_B(
    const float* __restrict__ WxT, const float* __restrict__ UT,
    const float* __restrict__ WxA, const float* __restrict__ UA,
    u16* __restrict__ dst) {
  __shared__ float tile[64][65];
  const int np0 = blockIdx.x * 64;
  const int r0 = blockIdx.y * 64;
  const int tx = threadIdx.x & 63, ty = threadIdx.x >> 6;

  const int np = np0 + tx;
  const int cell = np >> 11;
  const int n = np & 2047;
  const float* Wx = cell ? WxA : WxT;
  const float* U  = cell ? UA  : UT;
  int g = 0, j = 0, gc = 0;
  if (n < 2000) {
    g = n / 400; j = n % 400;
    gc = (g == 0) ? j : (g <= 2) ? 400 + j : (g == 3) ? 800 + j : 1200 + j;
  }
#pragma unroll
  for (int it = 0; it < 16; ++it) {
    int r = r0 + it * 4 + ty;
    float v = 0.f;
    if (n < 2000 && r < 800) {
      bool htside = (r < 400);
      int rr = htside ? r : r - 400;
      float wx = Wx[rr * 1600 + gc];
      float uu = U [rr * 1600 + gc];
      if (cell == 0) { // x = ht = h1
        if (htside) v = (g == 2) ? wx : wx + uu;   // f2 col: Wxf only
        else        v = (g == 1) ? 0.f : uu;        // f1 col: no ha term
      } else {          // x = ha = h2
        if (htside) v = (g == 2) ? 0.f : uu;
        else        v = (g == 1) ? wx : wx + uu;
      }
    }
    tile[tx][it * 4 + ty] = v;
  }
  __syncthreads();
#pragma unroll
  for (int it = 0; it < 16; ++it) {
    int npw = np0 + it * 4 + ty;
    dst[(size_t)npw * 832 + r0 + tx] = f2bf(tile[it * 4 + ty][tx]);
  }
}

__global__ void build_proj_B(const float* __restrict__ Wcur, const float* __restrict__ Wac,
                             const float* __restrict__ Wap, u16* __restrict__ dst) {
  int idx = blockIdx.x * 256 + threadIdx.x;
  if (idx >= 256 * 832) return;
  int n = idx / 832, r = idx % 832;
  float v = 0.f;
  if (r < 800) {
    if (n < 55) v = Wcur[r * 55 + n];
    else if (n < 107) { if (r < 400) v = Wac[r * 52 + (n - 55)]; }
    else if (n < 162) { if (r >= 400) v = Wap[(r - 400) * 55 + (n - 107)]; }
  }
  dst[idx] = f2bf(v);
}

// ---- GEMM (small shapes): 128x128 tile, 2-phase, round-2/3-verified --------
__global__ __launch_bounds__(256) void gemm_lds(
    const u16* __restrict__ A, const u16* __restrict__ Bt,
    u16* __restrict__ C, int K, int ldc) {
  __shared__ u16 As[128 * 64];
  __shared__ u16 Bs[128 * 64];
  const int tid = threadIdx.x;
  const int lane = tid & 63;
  const int wid = tid >> 6;

  const int nwg = gridDim.x * gridDim.y;
  const int bid = blockIdx.y * gridDim.x + blockIdx.x;
  const int swz = (bid & 7) * (nwg >> 3) + (bid >> 3);
  const int m0 = (swz / gridDim.x) * 128;
  const int n0 = (swz % gridDim.x) * 128;

  const int wm = (wid >> 1) << 6;
  const int wn = (wid & 1) << 6;

  f32x4 acc[4][4];
#pragma unroll
  for (int i = 0; i < 4; ++i)
#pragma unroll
    for (int j = 0; j < 4; ++j) acc[i][j] = (f32x4){0.f, 0.f, 0.f, 0.f};

  const int nkt = K >> 6;
  const int l8 = lane >> 3, lb = lane & 7;
  const int scol = (lb ^ l8) << 3;
  const u16* gA = A + (size_t)(m0 + wid * 8 + l8) * K + scol;
  const u16* gB = Bt + (size_t)(n0 + wid * 8 + l8) * K + scol;
  u16* lA = As + wid * 8 * 64;
  u16* lB = Bs + wid * 8 * 64;

  const int kq = (lane >> 4) << 3;
  const int rrow = lane & 15;

  for (int kt = 0; kt < nkt; ++kt) {
    __syncthreads();
    const u16* pa = gA + kt * 64;
    const u16* pb = gB + kt * 64;
#pragma unroll
    for (int c = 0; c < 4; ++c) {
      gload16(pa + (size_t)(c * 32) * K, lA + c * 2048);
      gload16(pb + (size_t)(c * 32) * K, lB + c * 2048);
    }
    __syncthreads();
#pragma unroll
    for (int half = 0; half < 2; ++half) {
      const int kk = half * 32 + kq;
      s16x8 af[4], bfr[4];
#pragma unroll
      for (int f = 0; f < 4; ++f) {
        int ar = wm + f * 16 + rrow;
        af[f] = *(const s16x8*)((const char*)As + ar * 128 + ((kk * 2) ^ ((ar & 7) << 4)));
        int br = wn + f * 16 + rrow;
        bfr[f] = *(const s16x8*)((const char*)Bs + br * 128 + ((kk * 2) ^ ((br & 7) << 4)));
      }
#pragma unroll
      for (int i = 0; i < 4; ++i)
#pragma unroll
        for (int j = 0; j < 4; ++j)
          acc[i][j] = __builtin_amdgcn_mfma_f32_16x16x32_bf16(af[i], bfr[j], acc[i][j], 0, 0, 0);
    }
  }

  const int crow0 = m0 + wm + ((lane >> 4) << 2);
  const int ccol0 = n0 + wn + rrow;
#pragma unroll
  for (int i = 0; i < 4; ++i)
#pragma unroll
    for (int j = 0; j < 4; ++j)
#pragma unroll
      for (int r = 0; r < 4; ++r)
        C[(size_t)(crow0 + i * 16 + r) * ldc + (ccol0 + j * 16)] = f2bf(acc[i][j][r]);
}

// ---- GEMM (big): 256x256 tile, 8 waves (2Mx4N), per-wave 128x64, 4 Gray
// phases/K-tile with 16 MFMA each, 2 LDS buffers, counted vmcnt ------------
// K=832 (13 tiles). Chunks: A c=rows[64c,+64), B c=cols[64c,+64); 1 gload16
// per thread per chunk. Stage tile t+1 during tile t: p0:{A0,A2} p1:{B0,B1}
// p2:{B2,B3} p3:{A1,A3}. Deadlines: {A0,A2,B0..B3}@p0, {A1,A3}@p2.
// Ledger (steady): wait vmcnt(4) at p0 (newest4 = A0',A2' just staged +
// deferred A1,A3 of this tile -> all p0-deadline chunks retired) and
// vmcnt(4) at p1 (retires A1,A3 before p2). Never drain in main loop.
// Tail (t=12): vmcnt(2)@p0, vmcnt(0)@p1. Phase: {stage; vmcnt; SB; BAR; SB;
// ds_reads; setprio1; 16 MFMA; setprio0; SB; BAR; SB} (rule 18 + T3/T4/T5).
#define PK8 832
#define NT8 13

__global__ __launch_bounds__(512, 2) void gemm_8p(
    const u16* __restrict__ A, const u16* __restrict__ Bt,
    u16* __restrict__ C, int ldc) {
  __shared__ char sm[131072];  // 2 buf x (A 32KB + B 32KB)
  const int tid = threadIdx.x;
  const int lane = tid & 63;
  const int wid = tid >> 6;

  const int nwg = gridDim.x * gridDim.y;  // 512, %8==0
  const int bid = blockIdx.y * gridDim.x + blockIdx.x;
  const int swz = (bid & 7) * (nwg >> 3) + (bid >> 3);
  const int m0 = (swz / gridDim.x) * 256;
  const int n0 = (swz % gridDim.x) * 256;

  const int wr = wid >> 2;  // 0..1 (M 128-row block)
  const int wc = wid & 3;   // 0..3 (N 64-col block)

  f32x4 acc[8][4];
#pragma unroll
  for (int i = 0; i < 8; ++i)
#pragma unroll
    for (int j = 0; j < 4; ++j) acc[i][j] = (f32x4){0.f, 0.f, 0.f, 0.f};

  // staging: linear LDS dest (wave-uniform base, implicit lane*16) +
  // pre-swizzled global source (rule 21); involution matches read-side XOR.
  const int rr8 = tid >> 3;                      // row within 64-row chunk
  const int scol = ((tid & 7) ^ (rr8 & 7)) << 3; // swizzled src col (u16)
  const u16* gA = A + (size_t)(m0 + rr8) * PK8 + scol;
  const u16* gB = Bt + (size_t)(n0 + rr8) * PK8 + scol;
  const int ldso = wid << 10;  // wave-uniform part of tid*16

#define SA8(kt, buf, c) gload16(gA + (size_t)((c) * 64) * PK8 + (kt) * 64,   \
      (u16*)(sm + (buf) * 65536 + (c) * 8192 + ldso))
#define SB8(kt, buf, c) gload16(gB + (size_t)((c) * 64) * PK8 + (kt) * 64,   \
      (u16*)(sm + (buf) * 65536 + 32768 + (c) * 8192 + ldso))
#define FENCE_BAR { __builtin_amdgcn_sched_barrier(0); __builtin_amdgcn_s_barrier(); __builtin_amdgcn_sched_barrier(0); }

  const int kq = (lane >> 4) << 3;
  const int rrow = lane & 15;

  // prologue: tile 0's 8 chunks in deadline order
  SA8(0, 0, 0); SA8(0, 0, 2);
  SB8(0, 0, 0); SB8(0, 0, 1); SB8(0, 0, 2); SB8(0, 0, 3);
  SA8(0, 0, 1); SA8(0, 0, 3);

  for (int t = 0; t < NT8; ++t) {
    const char* bb = sm + (t & 1) * 65536;
    const int nb = (t & 1) ^ 1;
    const bool st = (t + 1 < NT8);
    s16x8 afr[4][2], bfr[2][2];

    // ---- p0: (mh0, nh0) — read A[mh0], B[nh0] ----
    if (st) { SA8(t + 1, nb, 0); SA8(t + 1, nb, 2);
              asm volatile("s_waitcnt vmcnt(4)" ::: "memory"); }
    else    { asm volatile("s_waitcnt vmcnt(2)" ::: "memory"); }
    FENCE_BAR;
#pragma unroll
    for (int mf = 0; mf < 4; ++mf) {
      int ar = wr * 128 + mf * 16 + rrow;
      const char* ab = bb + ar * 128;
#pragma unroll
      for (int kh = 0; kh < 2; ++kh)
        afr[mf][kh] = *(const s16x8*)(ab + (((kh * 32 + kq) * 2) ^ ((ar & 7) << 4)));
    }
#pragma unroll
    for (int nf = 0; nf < 2; ++nf) {
      int br = wc * 64 + nf * 16 + rrow;
      const char* bbp = bb + 32768 + br * 128;
#pragma unroll
      for (int kh = 0; kh < 2; ++kh)
        bfr[nf][kh] = *(const s16x8*)(bbp + (((kh * 32 + kq) * 2) ^ ((br & 7) << 4)));
    }
    __builtin_amdgcn_s_setprio(1);
#pragma unroll
    for (int mf = 0; mf < 4; ++mf)
#pragma unroll
      for (int nf = 0; nf < 2; ++nf)
#pragma unroll
        for (int kh = 0; kh < 2; ++kh)
          acc[mf][nf] = __builtin_amdgcn_mfma_f32_16x16x32_bf16(
              afr[mf][kh], bfr[nf][kh], acc[mf][nf], 0, 0, 0);
    __builtin_amdgcn_s_setprio(0);
    FENCE_BAR;

    // ---- p1: (mh0, nh1) — reuse A, read B[nh1] ----
    if (st) { SB8(t + 1, nb, 0); SB8(t + 1, nb, 1);
              asm volatile("s_waitcnt vmcnt(4)" ::: "memory"); }
    else    { asm volatile("s_waitcnt vmcnt(0)" ::: "memory"); }
    FENCE_BAR;
#pragma unroll
    for (int nf = 0; nf < 2; ++nf) {
      int br = wc * 64 + 32 + nf * 16 + rrow;
      const char* bbp = bb + 32768 + br * 128;
#pragma unroll
      for (int kh = 0; kh < 2; ++kh)
        bfr[nf][kh] = *(const s16x8*)(bbp + (((kh * 32 + kq) * 2) ^ ((br & 7) << 4)));
    }
    __builtin_amdgcn_s_setprio(1);
#pragma unroll
    for (int mf = 0; mf < 4; ++mf)
#pragma unroll
      for (int nf = 0; nf < 2; ++nf)
#pragma unroll
        for (int kh = 0; kh < 2; ++kh)
          acc[mf][2 + nf] = __builtin_amdgcn_mfma_f32_16x16x32_bf16(
              afr[mf][kh], bfr[nf][kh], acc[mf][2 + nf], 0, 0, 0);
    __builtin_amdgcn_s_setprio(0);
    FENCE_BAR;

    // ---- p2: (mh1, nh1) — read A[mh1], reuse B ----
    if (st) { SB8(t + 1, nb, 2); SB8(t + 1, nb, 3); }
    FENCE_BAR;
#pragma unroll
    for (int mf = 0; mf < 4; ++mf) {
      int ar = wr * 128 + 64 + mf * 16 + rrow;
      const char* ab = bb + ar * 128;
#pragma unroll
      for (int kh = 0; kh < 2; ++kh)
        afr[mf][kh] = *(const s16x8*)(ab + (((kh * 32 + kq) * 2) ^ ((ar & 7) << 4)));
    }
    __builtin_amdgcn_s_setprio(1);
#pragma unroll
    for (int mf = 0; mf < 4; ++mf)
#pragma unroll
      for (int nf = 0; nf < 2; ++nf)
#pragma unroll
        for (int kh = 0; kh < 2; ++kh)
          acc[4 + mf][2 + nf] = __builtin_amdgcn_mfma_f32_16x16x32_bf16(
              afr[mf][kh], bfr[nf][kh], acc[4 + mf][2 + nf], 0, 0, 0);
    __builtin_amdgcn_s_setprio(0);
    FENCE_BAR;

    // ---- p3: (mh1, nh0) — reuse A, read B[nh0] ----
    if (st) { SA8(t + 1, nb, 1); SA8(t + 1, nb, 3); }
    FENCE_BAR;
#pragma unroll
    for (int nf = 0; nf < 2; ++nf) {
      int br = wc * 64 + nf * 16 + rrow;
      const char* bbp = bb + 32768 + br * 128;
#pragma unroll
      for (int kh = 0; kh < 2; ++kh)
        bfr[nf][kh] = *(const s16x8*)(bbp + (((kh * 32 + kq) * 2) ^ ((br & 7) << 4)));
    }
    __builtin_amdgcn_s_setprio(1);
#pragma unroll
    for (int mf = 0; mf < 4; ++mf)
#pragma unroll
      for (int nf = 0; nf < 2; ++nf)
#pragma unroll
        for (int kh = 0; kh < 2; ++kh)
          acc[4 + mf][nf] = __builtin_amdgcn_mfma_f32_16x16x32_bf16(
              afr[mf][kh], bfr[nf][kh], acc[4 + mf][nf], 0, 0, 0);
    __builtin_amdgcn_s_setprio(0);
    FENCE_BAR;
  }
#undef SA8
#undef SB8
#undef FENCE_BAR

  // ---- coalesced C-write: per-wave 128x64 bf16 tile staged in LDS (16 KiB
  // each, 8 waves = 128 KiB), then 128B-contiguous row stores.
  u16* eps = (u16*)(sm + wid * 16384);
#pragma unroll
  for (int i = 0; i < 8; ++i)
#pragma unroll
    for (int j = 0; j < 4; ++j)
#pragma unroll
      for (int r = 0; r < 4; ++r) {
        int row = i * 16 + ((lane >> 4) << 2) + r;
        int colb = (j * 16 + rrow) * 2;
        *(u16*)((char*)eps + row * 128 + (colb ^ ((row & 7) << 4))) = f2bf(acc[i][j][r]);
      }
  const size_t crowW = m0 + wr * 128;
  const int ccolW = n0 + wc * 64;
#pragma unroll
  for (int p = 0; p < 16; ++p) {
    int row = p * 8 + (lane >> 3);
    int segb = (lane & 7) * 16;
    i32x4 v = *(const i32x4*)((char*)eps + row * 128 + (segb ^ ((row & 7) << 4)));
    *(i32x4*)(C + (crowW + row) * (size_t)ldc + ccolW + (lane & 7) * 8) = v;
  }
}

// ---- epilogues -------------------------------------------------------------
// layer1: gates i,-,o,u at cols 0/800/1200 (+cell*2048); children zero -> c=i*u
__global__ void ep1(const u16* __restrict__ G,
                    const float* __restrict__ bT, const float* __restrict__ bA,
                    u16* __restrict__ Aout,
                    float* __restrict__ CT, float* __restrict__ CA) {
  int idx = blockIdx.x * 256 + threadIdx.x;
  if (idx >= 8192 * 200) return;
  int t = idx / 200, r = idx % 200;
  int cell = r / 100, j0 = (r % 100) * 4;
  const u16* g = G + (size_t)t * GLD + cell * 2048;
  const float* b = cell ? bA : bT;
  float* Cout = cell ? CA : CT;
  f32x4 ip = ld4bf(g + j0);
  f32x4 op = ld4bf(g + 800 + j0);
  f32x4 up = ld4bf(g + 1200 + j0);
  u64 hv = 0;
  f32x4 cv;
#pragma unroll
  for (int k = 0; k < 4; ++k) {
    int j = j0 + k;
    float c = sigf(ip[k] + b[j]) * tanhf_(up[k] + b[1200 + j]);
    float h = sigf(op[k] + b[800 + j]) * tanhf_(c);
    cv[k] = c;
    hv |= (u64)f2bf(h) << (16 * k);
  }
  *(u64*)(Aout + (size_t)t * 832 + cell * 400 + j0) = hv;
  *(f32x4*)(Cout + (size_t)t * 400 + j0) = cv;
}

// layer2/3: one thread does BOTH cells for (t, j-quad) -> c1/c2 read once.
__global__ void ep2(const u16* __restrict__ G,
                    const float* __restrict__ bT, const float* __restrict__ bA,
                    const float* __restrict__ C1, const float* __restrict__ C2,
                    u16* __restrict__ Aout,
                    float* __restrict__ CT, float* __restrict__ CA) {
  int idx = blockIdx.x * 256 + threadIdx.x;
  if (idx >= 8192 * 100) return;
  int t = idx / 100, j0 = (idx % 100) * 4;
  f32x4 c1 = *(const f32x4*)(C1 + (size_t)t * 400 + j0);
  f32x4 c2 = *(const f32x4*)(C2 + (size_t)t * 400 + j0);
#pragma unroll
  for (int cell = 0; cell < 2; ++cell) {
    const u16* g = G + (size_t)t * GLD + cell * 2048;
    const float* b = cell ? bA : bT;
    f32x4 ip  = ld4bf(g + j0);
    f32x4 f1p = ld4bf(g + 400 + j0);
    f32x4 f2p = ld4bf(g + 800 + j0);
    f32x4 op  = ld4bf(g + 1200 + j0);
    f32x4 up  = ld4bf(g + 1600 + j0);
    u64 hv = 0;
    f32x4 cv;
#pragma unroll
    for (int k = 0; k < 4; ++k) {
      int j = j0 + k;
      float c = sigf(ip[k] + b[j]) * tanhf_(up[k] + b[1200 + j])
              + sigf(f1p[k] + b[400 + j]) * c1[k]
              + sigf(f2p[k] + b[400 + j]) * c2[k];
      float h = sigf(op[k] + b[800 + j]) * tanhf_(c);
      cv[k] = c;
      hv |= (u64)f2bf(h) << (16 * k);
    }
    *(u64*)(Aout + (size_t)t * 832 + cell * 400 + j0) = hv;
    if (CT) {
      float* Cout = cell ? CA : CT;
      *(f32x4*)(Cout + (size_t)t * 400 + j0) = cv;
    }
  }
}

__global__ void ep_out(const u16* __restrict__ G,
                       const float* __restrict__ bcur, const float* __restrict__ bac,
                       const float* __restrict__ bap, float* __restrict__ out) {
  int idx = blockIdx.x * 256 + threadIdx.x;
  if (idx >= 8192 * 162) return;
  int t = idx / 162, j = idx % 162;
  float v = bf2f(G[(size_t)t * GLD + j]);
  if (j < 55)       out[t * 55 + j] = v + bcur[j];
  else if (j < 107) out[450560 + t * 52 + (j - 55)] = v + bac[j - 55];
  else              out[876544 + t * 55 + (j - 107)] = v + bap[j - 107];
}

// ---- launch ----------------------------------------------------------------
extern "C" void kernel_launch(void* const* d_in, const int* in_sizes, int n_in,
                              void* d_out, int out_size, void* d_ws, size_t ws_size,
                              hipStream_t stream) {
  const float* x_temp = (const float*)d_in[0];
  const float* x_air  = (const float*)d_in[1];
  const float* Wx_t1  = (const float*)d_in[2];
  const float* b_t1   = (const float*)d_in[4];
  const float* Wx_t2  = (const float*)d_in[5];
  const float* U_t2   = (const float*)d_in[6];
  const float* b_t2   = (const float*)d_in[7];
  const float* Wx_t3  = (const float*)d_in[8];
  const float* U_t3   = (const float*)d_in[9];
  const float* b_t3   = (const float*)d_in[10];
  const float* Wx_a1  = (const float*)d_in[11];
  const float* b_a1   = (const float*)d_in[13];
  const float* Wx_a2  = (const float*)d_in[14];
  const float* U_a2   = (const float*)d_in[15];
  const float* b_a2   = (const float*)d_in[16];
  const float* Wx_a3  = (const float*)d_in[17];
  const float* U_a3   = (const float*)d_in[18];
  const float* b_a3   = (const float*)d_in[19];
  const float* W_cur  = (const float*)d_in[20];
  const float* b_cur  = (const float*)d_in[21];
  const float* W_ac   = (const float*)d_in[22];
  const float* b_ac   = (const float*)d_in[23];
  const float* W_ap   = (const float*)d_in[24];
  const float* b_ap   = (const float*)d_in[25];

  char* ws = (char*)d_ws;
  u16*   A0t = (u16*)(ws + 0);          // [8192][64]
  u16*   A0a = (u16*)(ws + 1048576);
  u16*   B1t = (u16*)(ws + 2097152);    // [1664][64]
  u16*   B1a = (u16*)(ws + 2310144);
  u16*   Bp  = (u16*)(ws + 2523136);    // [256][832]
  u16*   A1  = (u16*)(ws + 2949120);    // [8192][832]  (ht|ha|pad)
  u16*   A2  = (u16*)(ws + 16580608);
  u16*   A3  = (u16*)(ws + 30212096);
  float* Ct  = (float*)(ws + 43843584); // [8192][400]
  float* Ca  = (float*)(ws + 56950784);
  float* C2t = (float*)(ws + 70057984);
  float* C2a = (float*)(ws + 83165184);
  u16*   B2  = (u16*)(ws + 96272384);   // [4096][832] (t rows 0..2047, a rows 2048..)
  u16*   B3  = (u16*)(ws + 103088128);
  u16*   G   = (u16*)(ws + 109903872);  // [8192][4096] bf16
  float* out = (float*)d_out;

  dim3 blk(256);
  zero_pads<<<768, blk, 0, stream>>>(A1, A2, A3);
  pad_cast<<<2048, blk, 0, stream>>>(x_temp, A0t, 55, 64, 8192);
  pad_cast<<<2048, blk, 0, stream>>>(x_air,  A0a, 55, 64, 8192);
  transpose_cast<<<416, blk, 0, stream>>>(Wx_t1, B1t, 55, 1600);
  transpose_cast<<<416, blk, 0, stream>>>(Wx_a1, B1a, 55, 1600);
  build_cell_B<<<dim3(64, 13), blk, 0, stream>>>(Wx_t2, U_t2, Wx_a2, U_a2, B2);
  build_cell_B<<<dim3(64, 13), blk, 0, stream>>>(Wx_t3, U_t3, Wx_a3, U_a3, B3);
  build_proj_B<<<832, blk, 0, stream>>>(W_cur, W_ac, W_ap, Bp);

  // layer 1 (two GEMMs, one merged epilogue)
  gemm_lds<<<dim3(13, 64), blk, 0, stream>>>(A0t, B1t, G, 64, GLD);
  gemm_lds<<<dim3(13, 64), blk, 0, stream>>>(A0a, B1a, G + 2048, 64, GLD);
  ep1<<<6400, blk, 0, stream>>>(G, b_t1, b_a1, A1, Ct, Ca);
  // layer 2 (one merged GEMM, 8-wave 256x256 pipelined)
  gemm_8p<<<dim3(16, 32), dim3(512), 0, stream>>>(A1, B2, G, GLD);
  ep2<<<3200, blk, 0, stream>>>(G, b_t2, b_a2, Ct, Ca, A2, C2t, C2a);
  // layer 3 (c outputs dead -> skip)
  gemm_8p<<<dim3(16, 32), dim3(512), 0, stream>>>(A2, B3, G, GLD);
  ep2<<<3200, blk, 0, stream>>>(G, b_t3, b_a3, C2t, C2a, A3, nullptr, nullptr);
  // projections
  gemm_lds<<<dim3(2, 64), blk, 0, stream>>>(A3, Bp, G, 832, GLD);
  ep_out<<<5184, blk, 0, stream>>>(G, b_cur, b_ac, b_ap, out);
}